// Round 13
// baseline (213.376 us; speedup 1.0000x reference)
//
#include <hip/hip_runtime.h>
#include <cstdint>
#include <cstddef>

#define SCALE  0.08838834764831845f   // 128^-0.5
#define EPS_   1e-8f
#define LN_EPS_ 1e-5f

typedef unsigned short ushort_t;
typedef unsigned int uint_t;
typedef __attribute__((ext_vector_type(8))) short short8;
typedef __attribute__((ext_vector_type(4))) float f32x4;

// ---------------- workspace layout (float offsets), 25.5 MB ----------------
constexpr int OFF_GFD   = 0;        // 256   (f_w1@g_w)/DELTA  [h][2]
constexpr int OFF_CB    = 256;      // 128   f_w1@g_b + f_b1
constexpr int OFF_QB    = 384;      // 64
constexpr int OFF_SP    = 448;      // 128
constexpr int OFF_OQ    = 576;      // 16384 interleaved (off, qf*scale)
constexpr int OFF_SLOTS = 16960;    // 8192
constexpr int OFF_ZP    = 25152;    // 8192    [b][128][8]
constexpr int OFF_PP    = 33344;    // 16384   [b][128][8][2]
constexpr int OFF_UP    = 49728;    // 1048576 [b][128][8][128]
constexpr int OFF_WKB   = 1098304;  // bf16 [128][128] = 8192 float-slots
constexpr int OFF_WVB   = 1106496;  // 8192
constexpr int OFF_FW2T  = 1114688;  // f32 f_w2^T 16384
constexpr int OFF_BKT   = 1131072;  // uint [b][64 dp][4096 n] = 2097152 float-slots
constexpr int OFF_BV    = 3228224;  // bf16 [b][4096][128] = 2097152 float-slots
constexpr int OFF_AB    = 5325376;  // bf16 inputs [32768][128] = 1048576 float-slots
// end: 6373952 floats

__device__ __forceinline__ float waveReduceSum(float v) {
#pragma unroll
  for (int m = 1; m < 64; m <<= 1) v += __shfl_xor(v, m, 64);
  return v;
}
__device__ __forceinline__ float bf2f(uint_t u) { return __uint_as_float(u << 16); }
__device__ __forceinline__ ushort_t f2bf(float f) {
  uint_t u = __float_as_uint(f);
  return (ushort_t)((u + 0x7fffu + ((u >> 16) & 1u)) >> 16);
}

// half-row dot (e-range [h*64, h*64+64)), 16 independent float4 loads
__device__ __forceinline__ float halfDot(const float* __restrict__ Wrow,
                                         const float* xv, int h) {
  const float4* wr = (const float4*)Wrow + h * 16;
  const float4* xr = (const float4*)xv + h * 16;
  float4 a = {0.f, 0.f, 0.f, 0.f};
#pragma unroll
  for (int i = 0; i < 16; ++i) {
    float4 wv = wr[i], xq = xr[i];
    a.x = fmaf(wv.x, xq.x, a.x);
    a.y = fmaf(wv.y, xq.y, a.y);
    a.z = fmaf(wv.z, xq.z, a.z);
    a.w = fmaf(wv.w, xq.w, a.w);
  }
  return (a.x + a.y) + (a.z + a.w);
}

// quarter-row dot (e-range [h*32, h*32+32)), 8 independent float4 loads
__device__ __forceinline__ float quarterDot(const float* __restrict__ Wrow,
                                            const float* xv, int h) {
  const float4* wr = (const float4*)Wrow + h * 8;
  const float4* xr = (const float4*)xv + h * 8;
  float4 a = {0.f, 0.f, 0.f, 0.f};
#pragma unroll
  for (int i = 0; i < 8; ++i) {
    float4 wv = wr[i], xq = xr[i];
    a.x = fmaf(wv.x, xq.x, a.x);
    a.y = fmaf(wv.y, xq.y, a.y);
    a.z = fmaf(wv.z, xq.z, a.z);
    a.w = fmaf(wv.w, xq.w, a.w);
  }
  return (a.x + a.y) + (a.z + a.w);
}
__device__ __forceinline__ float quadSum(float v) {
  v += __shfl_xor(v, 1, 64);
  v += __shfl_xor(v, 2, 64);
  return v;
}

// ---------------- fold weights + init copies + input cast ----------------
__global__ __launch_bounds__(256) void kFold(
    const float* __restrict__ f_w1, const float* __restrict__ Wk,
    const float* __restrict__ Wv, const float* __restrict__ g_w,
    const float* __restrict__ g_b, const float* __restrict__ f_b1,
    const float* __restrict__ f_w2, const float* __restrict__ slots_init,
    const float* __restrict__ S_p0, const float* __restrict__ inputs,
    float* __restrict__ ws) {
  int blk = blockIdx.x, tid = threadIdx.x;
  if (blk < 128) {
    int isV = blk >> 6;
    int idx = (blk & 63) * 256 + tid;           // 0..16383  (h*128+e)
    int h = idx >> 7, e = idx & 127;
    const float* Wm = isV ? Wv : Wk;
    float a = 0.f;
#pragma unroll 4
    for (int d = 0; d < 128; ++d) a = fmaf(f_w1[h * 128 + d], Wm[d * 128 + e], a);
    ((ushort_t*)(ws + (isV ? OFF_WVB : OFF_WKB)))[idx] = f2bf(a);
  } else if (blk == 128) {
    int h = tid >> 1, c = tid & 1;
    float a = 0.f;
    for (int d = 0; d < 128; ++d) a = fmaf(f_w1[h * 128 + d], g_w[d * 2 + c], a);
    ws[OFF_GFD + tid] = a * 0.2f;               // /DELTA (DELTA=5)
  } else if (blk == 129) {
    if (tid < 128) {
      float a = f_b1[tid];
      for (int d = 0; d < 128; ++d) a = fmaf(f_w1[tid * 128 + d], g_b[d], a);
      ws[OFF_CB + tid] = a;
    }
  } else if (blk == 130) {
    for (int i = tid; i < 16384; i += 256)
      ws[OFF_FW2T + (i & 127) * 128 + (i >> 7)] = f_w2[i];
  } else if (blk < 135) {
    int base = (blk - 131) * 2048 + tid * 8;    // slots copy, 8 floats/thread
    float4 a = *(const float4*)&slots_init[base];
    float4 b = *(const float4*)&slots_init[base + 4];
    *(float4*)&ws[OFF_SLOTS + base] = a;
    *(float4*)&ws[OFF_SLOTS + base + 4] = b;
  } else if (blk == 135) {
    if (tid < 128) ws[OFF_SP + tid] = S_p0[tid];
  } else {
    // input cast: blocks 136..391, 8 floats per thread
    int idx = (blk - 136) * 256 + tid;          // 0..65535
    const float4* src = (const float4*)(inputs + (size_t)idx * 8);
    float4 a = src[0], b = src[1];
    uint_t p0 = (uint_t)f2bf(a.x) | ((uint_t)f2bf(a.y) << 16);
    uint_t p1 = (uint_t)f2bf(a.z) | ((uint_t)f2bf(a.w) << 16);
    uint_t p2 = (uint_t)f2bf(b.x) | ((uint_t)f2bf(b.y) << 16);
    uint_t p3 = (uint_t)f2bf(b.z) | ((uint_t)f2bf(b.w) << 16);
    ((uint4*)((ushort_t*)(ws + OFF_AB)))[idx] = make_uint4(p0, p1, p2, p3);
  }
}

// ---------------- MFMA base GEMMs (64-row blocks) + initial q ----------------
struct QSm { float yl[128]; float ql[128]; float red[4]; float red2[4]; };

__device__ void doQ(int bs, const float* __restrict__ Wq,
                    const float* __restrict__ f_b2,
                    const float* __restrict__ lnsg,
                    const float* __restrict__ lnsb,
                    float* __restrict__ ws, QSm& S) {
  int t = threadIdx.x, w = t >> 6, lane = t & 63;
  int d = w * 32 + (lane >> 1), h = lane & 1;
  const float* FW2T = ws + OFF_FW2T;
  float x = ws[OFF_SLOTS + bs * 128 + d];
  float m1 = waveReduceSum(h == 0 ? x : 0.f);
  float m2 = waveReduceSum(h == 0 ? x * x : 0.f);
  if (lane == 0) { S.red[w] = m1; S.red2[w] = m2; }
  __syncthreads();
  float mean = (S.red[0] + S.red[1] + S.red[2] + S.red[3]) * (1.f / 128.f);
  float var = (S.red2[0] + S.red2[1] + S.red2[2] + S.red2[3]) * (1.f / 128.f) - mean * mean;
  if (h == 0) S.yl[d] = (x - mean) * rsqrtf(var + LN_EPS_) * lnsg[d] + lnsb[d];
  __syncthreads();
  float q = halfDot(Wq + (size_t)d * 128, S.yl, h);
  q += __shfl_xor(q, 1, 64);
  if (h == 0) S.ql[d] = q;
  __syncthreads();
  float qv = waveReduceSum(h == 0 ? q * f_b2[d] : 0.f);
  if (lane == 0) S.red[w] = qv;
  float qf = halfDot(FW2T + (size_t)d * 128, S.ql, h);
  qf += __shfl_xor(qf, 1, 64);
  __syncthreads();
  if (t == 0) ws[OFF_QB + bs] = (S.red[0] + S.red[1] + S.red[2] + S.red[3]) * SCALE;
  if (h == 0) {
    float sp0 = ws[OFF_SP + bs * 2 + 0], sp1 = ws[OFF_SP + bs * 2 + 1];
    float offd = -(sp0 * ws[OFF_GFD + d * 2 + 0] + sp1 * ws[OFF_GFD + d * 2 + 1]);
    ws[OFF_OQ + (bs * 128 + d) * 2 + 0] = offd;
    ws[OFF_OQ + (bs * 128 + d) * 2 + 1] = qf * SCALE;
  }
}

// grid: 1024 GEMM blocks (mat = blk>>9, rb = blk&511, 64 rows each) + 64 doQ
__global__ __launch_bounds__(256) void kBaseQ(const float* __restrict__ Wq,
                                              const float* __restrict__ f_b2,
                                              const float* __restrict__ lnsg,
                                              const float* __restrict__ lnsb,
                                              float* __restrict__ ws) {
  __shared__ __align__(16) char smem[17408];
  int blk = blockIdx.x;
  if (blk >= 1024) {      // initial q projection blocks
    doQ(blk - 1024, Wq, f_b2, lnsg, lnsb, ws, *reinterpret_cast<QSm*>(smem));
    return;
  }
  char* ep = smem;
  const ushort_t* ab = (const ushort_t*)(ws + OFF_AB);
  int tid = threadIdx.x, w = tid >> 6, l = tid & 63;
  int lr = l & 15, lg = l >> 4;
  int mat = blk >> 9;
  int rb = blk & 511;                 // 0..511 (64-row block index)
  int b = rb >> 6;
  int n0 = (rb & 63) * 64;            // pixel base within batch
  const ushort_t* Wg = (const ushort_t*)(ws + (mat ? OFF_WVB : OFF_WKB));

  short8 afrag[4];
#pragma unroll
  for (int ks = 0; ks < 4; ++ks) {
    size_t row = (size_t)b * 4096 + n0 + w * 16 + lr;
    afrag[ks] = *(const short8*)(ab + row * 128 + ks * 32 + lg * 8);
  }
  float gf0a[8], gf1a[8], cba[8];
#pragma unroll
  for (int ct = 0; ct < 8; ++ct) {
    int c = ct * 16 + lr;
    gf0a[ct] = ws[OFF_GFD + c * 2 + 0];
    gf1a[ct] = ws[OFF_GFD + c * 2 + 1];
    cba[ct]  = ws[OFF_CB + c];
  }
  f32x4 acc[8];
#pragma unroll
  for (int ct = 0; ct < 8; ++ct) acc[ct] = (f32x4){0.f, 0.f, 0.f, 0.f};
#pragma unroll 2
  for (int ct = 0; ct < 8; ++ct) {
    short8 bfr[4];
#pragma unroll
    for (int ks = 0; ks < 4; ++ks)
      bfr[ks] = *(const short8*)(Wg + (ct * 16 + lr) * 128 + ks * 32 + lg * 8);
#pragma unroll
    for (int ks = 0; ks < 4; ++ks)
      acc[ct] = __builtin_amdgcn_mfma_f32_16x16x32_bf16(afrag[ks], bfr[ks], acc[ct], 0, 0, 0);
  }
#pragma unroll
  for (int ct = 0; ct < 8; ++ct) {
    int c = ct * 16 + lr;
    ushort_t pk[4];
#pragma unroll
    for (int r = 0; r < 4; ++r) {
      int nl = w * 16 + lg * 4 + r;
      int n = n0 + nl;
      float gy = -1.f + (float)(n >> 6) * (2.f / 63.f);
      float gx = -1.f + (float)(n & 63) * (2.f / 63.f);
      float o = acc[ct][r] + gy * gf0a[ct] + gx * gf1a[ct] + cba[ct];
      pk[r] = f2bf(o);
    }
    if (mat == 0) {
      int nl0 = w * 16 + lg * 4;
      int byte = (c * 128 + nl0 * 2) ^ ((c & 7) << 4);
      *(uint2*)(ep + byte) = make_uint2(
          (uint_t)pk[0] | ((uint_t)pk[1] << 16),
          (uint_t)pk[2] | ((uint_t)pk[3] << 16));
    } else {
      int nl0 = w * 16 + lg * 4;
#pragma unroll
      for (int r = 0; r < 4; ++r)
        *(ushort_t*)(ep + (nl0 + r) * 272 + c * 2) = pk[r];
    }
  }
  __syncthreads();
  if (mat == 0) {
    uint_t* outK = (uint_t*)(ws + OFF_BKT);
    for (int idx = tid; idx < 1024; idx += 256) {
      int dp = idx >> 4, j = idx & 15;
      int c0 = 2 * dp, c1 = 2 * dp + 1;
      uint2 aA = *(const uint2*)(ep + ((c0 * 128 + j * 8) ^ ((c0 & 7) << 4)));
      uint2 bA = *(const uint2*)(ep + ((c1 * 128 + j * 8) ^ ((c1 & 7) << 4)));
      uint4 o;
      o.x = (aA.x & 0xffffu) | (bA.x << 16);
      o.y = (aA.x >> 16) | (bA.x & 0xffff0000u);
      o.z = (aA.y & 0xffffu) | (bA.y << 16);
      o.w = (aA.y >> 16) | (bA.y & 0xffff0000u);
      *(uint4*)(outK + ((size_t)(b * 64 + dp)) * 4096 + n0 + j * 4) = o;
    }
  } else {
    ushort_t* outV = (ushort_t*)(ws + OFF_BV);
    for (int idx = tid; idx < 1024; idx += 256) {
      int nl = idx >> 4, j = idx & 15;
      uint4 v = *(const uint4*)(ep + nl * 272 + j * 16);
      *(uint4*)(outV + ((size_t)rb * 64 + nl) * 128 + j * 8) = v;
    }
  }
}

// ---------------- fused attention: 32-pixel chunks, 1024 blocks ----------------
__global__ __launch_bounds__(256) void kAttn(float* __restrict__ ws) {
  __shared__ __align__(16) float OFFl[8][128];
  __shared__ __align__(16) float QFl[8][128];
  __shared__ float tp[32][33];
  __shared__ __align__(16) float al[32][12];
  __shared__ float Ush[4][8][132];
  int b = blockIdx.x >> 7, chunk = blockIdx.x & 127;
  int tid = threadIdx.x, w = tid >> 6, lane = tid & 63;
  int sb = b * 8;
  int n0 = chunk * 32;
  // V prefetch: wave w covers pixels w*8..w*8+7, channel-pair c0
  int c0 = 2 * lane;
  const ushort_t* vp = (const ushort_t*)(ws + OFF_BV) +
                       ((size_t)(b * 4096 + n0 + w * 8)) * 128 + c0;
  uint_t varr[8];
#pragma unroll
  for (int i = 0; i < 8; ++i) varr[i] = *(const uint_t*)(vp + (size_t)i * 128);
  for (int f = tid; f < 1024; f += 256) {
    int s = f >> 7, d = f & 127;
    float2 oq = *(const float2*)&ws[OFF_OQ + ((sb + s) * 128 + d) * 2];
    OFFl[s][d] = oq.x;
    QFl[s][d] = oq.y;
  }
  float qbl[8];
#pragma unroll
  for (int s = 0; s < 8; ++s) qbl[s] = ws[OFF_QB + sb + s];
  __syncthreads();

  // phase 1: 2 lanes per pixel, each lane covers 8 d-pairs of wave's quarter
  int p = lane >> 1, half = lane & 1;
  int n = n0 + p;
  const uint_t* kpp = (const uint_t*)(ws + OFF_BKT) +
                      (size_t)b * 262144 + (size_t)(w * 16 + half * 8) * 4096 + n;
  float t[8];
#pragma unroll
  for (int s = 0; s < 8; ++s) t[s] = 0.f;
#pragma unroll
  for (int j = 0; j < 8; ++j) {
    uint_t v = kpp[(size_t)j * 4096];
    float k0 = bf2f(v & 0xffffu);
    float k1 = bf2f(v >> 16);
    int d0 = w * 32 + (half * 8 + j) * 2;
#pragma unroll
    for (int s = 0; s < 8; ++s) {
      float2 ofp = *(const float2*)&OFFl[s][d0];
      float2 qfp = *(const float2*)&QFl[s][d0];
      t[s] = fmaf(fmaxf(k0 + ofp.x, 0.f), qfp.x, t[s]);
      t[s] = fmaf(fmaxf(k1 + ofp.y, 0.f), qfp.y, t[s]);
    }
  }
#pragma unroll
  for (int s = 0; s < 8; ++s) {
    t[s] += __shfl_xor(t[s], 1, 64);     // merge half-pair
    if (half == 0) tp[p][s * 4 + w] = t[s];
  }
  __syncthreads();
  int p2 = lane & 31;
  float a[8], den = 0.f;
#pragma unroll
  for (int s = 0; s < 8; ++s)
    t[s] = tp[p2][s * 4 + 0] + tp[p2][s * 4 + 1] +
           tp[p2][s * 4 + 2] + tp[p2][s * 4 + 3] + qbl[s];
  float mx = t[0];
#pragma unroll
  for (int s = 1; s < 8; ++s) mx = fmaxf(mx, t[s]);
#pragma unroll
  for (int s = 0; s < 8; ++s) { a[s] = __expf(t[s] - mx); den += a[s]; }
  float inv = 1.0f / den;
#pragma unroll
  for (int s = 0; s < 8; ++s) a[s] = fmaf(a[s], inv, EPS_);
  if (w == 0) {
    int n2 = n0 + p2;
    float gy = -1.f + (float)(n2 >> 6) * (2.f / 63.f);
    float gx = -1.f + (float)(n2 & 63) * (2.f / 63.f);
    bool lo = (lane < 32);
    if (lo) {
#pragma unroll
      for (int s = 0; s < 8; ++s) al[p2][s] = a[s];
    }
#pragma unroll
    for (int s = 0; s < 8; ++s) {
      float z = waveReduceSum(lo ? a[s] : 0.f);
      float p0 = waveReduceSum(lo ? a[s] * gy : 0.f);
      float p1 = waveReduceSum(lo ? a[s] * gx : 0.f);
      if (lane == 0) {
        ws[OFF_ZP + (b * 128 + chunk) * 8 + s] = z;
        ws[OFF_PP + ((b * 128 + chunk) * 8 + s) * 2 + 0] = p0;
        ws[OFF_PP + ((b * 128 + chunk) * 8 + s) * 2 + 1] = p1;
      }
    }
  }
  __syncthreads();

  // phase 2: channel-pair-per-lane over this wave's 8 pixels (V prefetched)
  float offv0[8], offv1[8];
#pragma unroll
  for (int s = 0; s < 8; ++s) {
    float2 of2 = *(const float2*)&OFFl[s][c0];
    offv0[s] = of2.x;
    offv1[s] = of2.y;
  }
  float Ua0[8], Ua1[8];
#pragma unroll
  for (int s = 0; s < 8; ++s) { Ua0[s] = 0.f; Ua1[s] = 0.f; }
#pragma unroll
  for (int i = 0; i < 8; ++i) {
    uint_t vraw = varr[i];
    float v0 = bf2f(vraw & 0xffffu);
    float v1 = bf2f(vraw >> 16);
    int ii = w * 8 + i;
    float4 a0 = *(const float4*)&al[ii][0];
    float4 a1 = *(const float4*)&al[ii][4];
    float asv[8] = {a0.x, a0.y, a0.z, a0.w, a1.x, a1.y, a1.z, a1.w};
#pragma unroll
    for (int s = 0; s < 8; ++s) {
      Ua0[s] = fmaf(asv[s], fmaxf(v0 + offv0[s], 0.f), Ua0[s]);
      Ua1[s] = fmaf(asv[s], fmaxf(v1 + offv1[s], 0.f), Ua1[s]);
    }
  }
#pragma unroll
  for (int s = 0; s < 8; ++s) {
    Ush[w][s][c0] = Ua0[s];
    Ush[w][s][c0 + 1] = Ua1[s];
  }
  __syncthreads();
  for (int f = tid; f < 1024; f += 256) {
    int s = f >> 7, c = f & 127;
    float v = Ush[0][s][c] + Ush[1][s][c] + Ush[2][s][c] + Ush[3][s][c];
    ws[OFF_UP + ((size_t)(b * 128 + chunk) * 8 + s) * 128 + c] = v;
  }
}

// ---------------- fused: finalize + GRU + post-MLP + next-iter q ----------------
__global__ __launch_bounds__(512) void kCQ(
    const float* __restrict__ Wq, const float* __restrict__ f_w2,
    const float* __restrict__ f_b2, const float* __restrict__ wih,
    const float* __restrict__ whh, const float* __restrict__ bih,
    const float* __restrict__ bhh, const float* __restrict__ mw1,
    const float* __restrict__ mb1, const float* __restrict__ mw2,
    const float* __restrict__ mb2, const float* __restrict__ lnpg,
    const float* __restrict__ lnpb, const float* __restrict__ lnsg,
    const float* __restrict__ lnsb, const float* __restrict__ S_r,
    const float* __restrict__ S_s, float* __restrict__ ws,
    float* __restrict__ out, int last) {
  int bs = blockIdx.x;
  int t = threadIdx.x;
  if (bs == 64) {         // only on last iter: S_r / S_s passthrough
    if (t < 256) out[8320 + t] = S_r[t];
    else if (t < 384) out[8576 + t - 256] = S_s[t - 256];
    return;
  }
  int b = bs >> 3, s = bs & 7;
  int w = t >> 6, lane = t & 63;
  int d = t >> 2, h = t & 3;
  __shared__ __align__(16) float ul[128], xl[128], sl[128], yl[128], hml[128];
  __shared__ float red[8], red2[8];
  const float* FW2T = ws + OFF_FW2T;
  // Z / P over 128 chunks: each lane handles chunk lane and lane+64
  float zv = ws[OFF_ZP + (b * 128 + lane) * 8 + s] +
             ws[OFF_ZP + (b * 128 + 64 + lane) * 8 + s];
  float2 pva = *(const float2*)&ws[OFF_PP + ((size_t)((b * 128 + lane) * 8 + s)) * 2];
  float2 pvb = *(const float2*)&ws[OFF_PP + ((size_t)((b * 128 + 64 + lane) * 8 + s)) * 2];
  float Z = waveReduceSum(zv);
  float P0 = waveReduceSum(pva.x + pvb.x);
  float P1 = waveReduceSum(pva.y + pvb.y);
  float invZ = 1.f / Z, sp0 = P0 * invZ, sp1 = P1 * invZ;
  float u = 0.f;
  const float* up = ws + OFF_UP + ((size_t)(b * 128 + h * 32) * 8 + s) * 128 + d;
#pragma unroll
  for (int ch = 0; ch < 32; ++ch) u += up[(size_t)ch * 1024];
  u = quadSum(u);
  if (h == 0) { ul[d] = u * invZ; sl[d] = ws[OFF_SLOTS + bs * 128 + d]; }
  if (t == 0) {
    ws[OFF_SP + bs * 2 + 0] = sp0;
    ws[OFF_SP + bs * 2 + 1] = sp1;
    if (last) {
      out[8192 + bs * 2 + 0] = sp0;
      out[8192 + bs * 2 + 1] = sp1;
    }
  }
  __syncthreads();
  float xa = quadSum(quarterDot(f_w2 + (size_t)d * 128, ul, h));
  if (h == 0) xl[d] = xa + f_b2[d];
  __syncthreads();
  float ir = quarterDot(wih + (size_t)d * 128, xl, h);
  float iz = quarterDot(wih + (size_t)(128 + d) * 128, xl, h);
  float in_ = quarterDot(wih + (size_t)(256 + d) * 128, xl, h);
  float hr = quarterDot(whh + (size_t)d * 128, sl, h);
  float hz = quarterDot(whh + (size_t)(128 + d) * 128, sl, h);
  float hn = quarterDot(whh + (size_t)(256 + d) * 128, sl, h);
  ir = quadSum(ir); iz = quadSum(iz); in_ = quadSum(in_);
  hr = quadSum(hr); hz = quadSum(hz); hn = quadSum(hn);
  float hnew = 0.f;
  if (h == 0) {
    float rg = 1.f / (1.f + __expf(-(ir + bih[d] + hr + bhh[d])));
    float zg = 1.f / (1.f + __expf(-(iz + bih[128 + d] + hz + bhh[128 + d])));
    float ng = tanhf(in_ + bih[256 + d] + rg * (hn + bhh[256 + d]));
    hnew = (1.f - zg) * ng + zg * sl[d];
  }
  float m1 = waveReduceSum(h == 0 ? hnew : 0.f);
  float m2 = waveReduceSum(h == 0 ? hnew * hnew : 0.f);
  if (lane == 0) { red[w] = m1; red2[w] = m2; }
  __syncthreads();
  float mean = 0.f, var = 0.f;
#pragma unroll
  for (int i = 0; i < 8; ++i) { mean += red[i]; var += red2[i]; }
  mean *= (1.f / 128.f);
  var = var * (1.f / 128.f) - mean * mean;
  if (h == 0) yl[d] = (hnew - mean) * rsqrtf(var + LN_EPS_) * lnpg[d] + lnpb[d];
  __syncthreads();
  float hm = quadSum(quarterDot(mw1 + (size_t)d * 128, yl, h));
  if (h == 0) hml[d] = fmaxf(hm + mb1[d], 0.f);
  __syncthreads();
  float oa = quadSum(quarterDot(mw2 + (size_t)d * 128, hml, h));
  float o = 0.f;
  if (h == 0) {
    o = hnew + mb2[d] + oa;
    ws[OFF_SLOTS + bs * 128 + d] = o;
    if (last) out[bs * 128 + d] = o;
  }
  float n1 = waveReduceSum(h == 0 ? o : 0.f);
  float n2 = waveReduceSum(h == 0 ? o * o : 0.f);
  if (lane == 0) { red[w] = n1; red2[w] = n2; }
  __syncthreads();
  float mean2 = 0.f, var2 = 0.f;
#pragma unroll
  for (int i = 0; i < 8; ++i) { mean2 += red[i]; var2 += red2[i]; }
  mean2 *= (1.f / 128.f);
  var2 = var2 * (1.f / 128.f) - mean2 * mean2;
  if (h == 0) yl[d] = (o - mean2) * rsqrtf(var2 + LN_EPS_) * lnsg[d] + lnsb[d];
  __syncthreads();
  float q = quadSum(quarterDot(Wq + (size_t)d * 128, yl, h));
  if (h == 0) xl[d] = q;
  __syncthreads();
  float qv = waveReduceSum(h == 0 ? q * f_b2[d] : 0.f);
  if (lane == 0) red[w] = qv;
  float qf = quadSum(quarterDot(FW2T + (size_t)d * 128, xl, h));
  __syncthreads();
  if (t == 0) {
    float qb = 0.f;
#pragma unroll
    for (int i = 0; i < 8; ++i) qb += red[i];
    ws[OFF_QB + bs] = qb * SCALE;
  }
  if (h == 0) {
    float offd = -(sp0 * ws[OFF_GFD + d * 2 + 0] + sp1 * ws[OFF_GFD + d * 2 + 1]);
    ws[OFF_OQ + (bs * 128 + d) * 2 + 0] = offd;
    ws[OFF_OQ + (bs * 128 + d) * 2 + 1] = qf * SCALE;
  }
}

extern "C" void kernel_launch(void* const* d_in, const int* in_sizes, int n_in,
                              void* d_out, int out_size, void* d_ws, size_t ws_size,
                              hipStream_t stream) {
  const float* inputs     = (const float*)d_in[0];
  const float* slots_init = (const float*)d_in[1];
  const float* S_p0       = (const float*)d_in[2];
  const float* S_s        = (const float*)d_in[3];
  const float* S_r        = (const float*)d_in[4];
  const float* Wq   = (const float*)d_in[5];
  const float* Wk   = (const float*)d_in[6];
  const float* Wv   = (const float*)d_in[7];
  const float* g_w  = (const float*)d_in[8];
  const float* g_b  = (const float*)d_in[9];
  const float* f_w1 = (const float*)d_in[10];
  const float* f_b1 = (const float*)d_in[11];
  const float* f_w2 = (const float*)d_in[12];
  const float* f_b2 = (const float*)d_in[13];
  const float* gwih = (const float*)d_in[14];
  const float* gwhh = (const float*)d_in[15];
  const float* gbih = (const float*)d_in[16];
  const float* gbhh = (const float*)d_in[17];
  const float* mw1  = (const float*)d_in[18];
  const float* mb1  = (const float*)d_in[19];
  const float* mw2  = (const float*)d_in[20];
  const float* mb2  = (const float*)d_in[21];
  const float* lnsg = (const float*)d_in[22];
  const float* lnsb = (const float*)d_in[23];
  const float* lnpg = (const float*)d_in[24];
  const float* lnpb = (const float*)d_in[25];
  float* ws  = (float*)d_ws;
  float* out = (float*)d_out;

  kFold<<<392, 256, 0, stream>>>(f_w1, Wk, Wv, g_w, g_b, f_b1, f_w2,
                                 slots_init, S_p0, inputs, ws);
  kBaseQ<<<1088, 256, 0, stream>>>(Wq, f_b2, lnsg, lnsb, ws);
  for (int it = 0; it < 3; ++it) {
    int last = (it == 2);
    kAttn<<<1024, 256, 0, stream>>>(ws);
    kCQ<<<64 + last, 512, 0, stream>>>(Wq, f_w2, f_b2, gwih, gwhh, gbih, gbhh,
                                       mw1, mb1, mw2, mb2, lnpg, lnpb,
                                       lnsg, lnsb, S_r, S_s, ws, out, last);
  }
}

// Round 14
// 157.820 us; speedup vs baseline: 1.3520x; 1.3520x over previous
//
#include <hip/hip_runtime.h>
#include <cstdint>
#include <cstddef>

#define SCALE  0.08838834764831845f   // 128^-0.5
#define EPS_   1e-8f
#define LN_EPS_ 1e-5f

typedef unsigned short ushort_t;
typedef unsigned int uint_t;
typedef __attribute__((ext_vector_type(8))) short short8;
typedef __attribute__((ext_vector_type(4))) float f32x4;

// ---------------- workspace layout (float offsets), 23.3 MB ----------------
constexpr int OFF_GFD   = 0;        // 256   (f_w1@g_w)/DELTA  [h][2]
constexpr int OFF_CB    = 256;      // 128   f_w1@g_b + f_b1
constexpr int OFF_QB    = 384;      // 64
constexpr int OFF_SP    = 448;      // 128
constexpr int OFF_OQ    = 576;      // 16384 interleaved (off, qf*scale)
constexpr int OFF_SLOTS = 16960;    // 8192
constexpr int OFF_ZP    = 25152;    // 4096   [b][64][8]
constexpr int OFF_PP    = 29248;    // 8192   [b][64][8][2]
constexpr int OFF_UP    = 37440;    // 524288 [b][64][8][128]
constexpr int OFF_WKB   = 561728;   // bf16 [128][128] = 8192 float-slots
constexpr int OFF_WVB   = 569920;   // 8192
constexpr int OFF_FW2T  = 578112;   // f32 f_w2^T 16384
constexpr int OFF_BKT   = 594496;   // uint [b][64 dp][4096 n] = 2097152 float-slots
constexpr int OFF_BV    = 2691648;  // bf16 [b][4096][128] = 2097152 float-slots
constexpr int OFF_AB    = 4788800;  // bf16 inputs [32768][128] = 1048576 float-slots
// end: 5837376 floats

__device__ __forceinline__ float waveReduceSum(float v) {
#pragma unroll
  for (int m = 1; m < 64; m <<= 1) v += __shfl_xor(v, m, 64);
  return v;
}
__device__ __forceinline__ float bf2f(uint_t u) { return __uint_as_float(u << 16); }
__device__ __forceinline__ ushort_t f2bf(float f) {
  uint_t u = __float_as_uint(f);
  return (ushort_t)((u + 0x7fffu + ((u >> 16) & 1u)) >> 16);
}

// half-row dot (e-range [h*64, h*64+64)), 16 independent float4 loads
__device__ __forceinline__ float halfDot(const float* __restrict__ Wrow,
                                         const float* xv, int h) {
  const float4* wr = (const float4*)Wrow + h * 16;
  const float4* xr = (const float4*)xv + h * 16;
  float4 a = {0.f, 0.f, 0.f, 0.f};
#pragma unroll
  for (int i = 0; i < 16; ++i) {
    float4 wv = wr[i], xq = xr[i];
    a.x = fmaf(wv.x, xq.x, a.x);
    a.y = fmaf(wv.y, xq.y, a.y);
    a.z = fmaf(wv.z, xq.z, a.z);
    a.w = fmaf(wv.w, xq.w, a.w);
  }
  return (a.x + a.y) + (a.z + a.w);
}

// quarter-row dot (e-range [h*32, h*32+32)), 8 independent float4 loads
__device__ __forceinline__ float quarterDot(const float* __restrict__ Wrow,
                                            const float* xv, int h) {
  const float4* wr = (const float4*)Wrow + h * 8;
  const float4* xr = (const float4*)xv + h * 8;
  float4 a = {0.f, 0.f, 0.f, 0.f};
#pragma unroll
  for (int i = 0; i < 8; ++i) {
    float4 wv = wr[i], xq = xr[i];
    a.x = fmaf(wv.x, xq.x, a.x);
    a.y = fmaf(wv.y, xq.y, a.y);
    a.z = fmaf(wv.z, xq.z, a.z);
    a.w = fmaf(wv.w, xq.w, a.w);
  }
  return (a.x + a.y) + (a.z + a.w);
}
__device__ __forceinline__ float quadSum(float v) {
  v += __shfl_xor(v, 1, 64);
  v += __shfl_xor(v, 2, 64);
  return v;
}

// ---------------- fold weights + init copies + input cast ----------------
__global__ __launch_bounds__(256) void kFold(
    const float* __restrict__ f_w1, const float* __restrict__ Wk,
    const float* __restrict__ Wv, const float* __restrict__ g_w,
    const float* __restrict__ g_b, const float* __restrict__ f_b1,
    const float* __restrict__ f_w2, const float* __restrict__ slots_init,
    const float* __restrict__ S_p0, const float* __restrict__ inputs,
    float* __restrict__ ws) {
  int blk = blockIdx.x, tid = threadIdx.x;
  if (blk < 128) {
    int isV = blk >> 6;
    int idx = (blk & 63) * 256 + tid;           // 0..16383  (h*128+e)
    int h = idx >> 7, e = idx & 127;
    const float* Wm = isV ? Wv : Wk;
    float a = 0.f;
#pragma unroll 4
    for (int d = 0; d < 128; ++d) a = fmaf(f_w1[h * 128 + d], Wm[d * 128 + e], a);
    ((ushort_t*)(ws + (isV ? OFF_WVB : OFF_WKB)))[idx] = f2bf(a);
  } else if (blk == 128) {
    int h = tid >> 1, c = tid & 1;
    float a = 0.f;
    for (int d = 0; d < 128; ++d) a = fmaf(f_w1[h * 128 + d], g_w[d * 2 + c], a);
    ws[OFF_GFD + tid] = a * 0.2f;               // /DELTA (DELTA=5)
  } else if (blk == 129) {
    if (tid < 128) {
      float a = f_b1[tid];
      for (int d = 0; d < 128; ++d) a = fmaf(f_w1[tid * 128 + d], g_b[d], a);
      ws[OFF_CB + tid] = a;
    }
  } else if (blk == 130) {
    for (int i = tid; i < 16384; i += 256)
      ws[OFF_FW2T + (i & 127) * 128 + (i >> 7)] = f_w2[i];
  } else if (blk < 135) {
    int base = (blk - 131) * 2048 + tid * 8;    // slots copy, 8 floats/thread
    float4 a = *(const float4*)&slots_init[base];
    float4 b = *(const float4*)&slots_init[base + 4];
    *(float4*)&ws[OFF_SLOTS + base] = a;
    *(float4*)&ws[OFF_SLOTS + base + 4] = b;
  } else if (blk == 135) {
    if (tid < 128) ws[OFF_SP + tid] = S_p0[tid];
  } else {
    // input cast: blocks 136..391, 8 floats per thread
    int idx = (blk - 136) * 256 + tid;          // 0..65535
    const float4* src = (const float4*)(inputs + (size_t)idx * 8);
    float4 a = src[0], b = src[1];
    uint_t p0 = (uint_t)f2bf(a.x) | ((uint_t)f2bf(a.y) << 16);
    uint_t p1 = (uint_t)f2bf(a.z) | ((uint_t)f2bf(a.w) << 16);
    uint_t p2 = (uint_t)f2bf(b.x) | ((uint_t)f2bf(b.y) << 16);
    uint_t p3 = (uint_t)f2bf(b.z) | ((uint_t)f2bf(b.w) << 16);
    ((uint4*)((ushort_t*)(ws + OFF_AB)))[idx] = make_uint4(p0, p1, p2, p3);
  }
}

// ---------------- MFMA base GEMMs (64-row blocks) + initial q ----------------
struct QSm { float yl[128]; float ql[128]; float red[4]; float red2[4]; };

__device__ void doQ(int bs, const float* __restrict__ Wq,
                    const float* __restrict__ f_b2,
                    const float* __restrict__ lnsg,
                    const float* __restrict__ lnsb,
                    float* __restrict__ ws, QSm& S) {
  int t = threadIdx.x, w = t >> 6, lane = t & 63;
  int d = w * 32 + (lane >> 1), h = lane & 1;
  const float* FW2T = ws + OFF_FW2T;
  float x = ws[OFF_SLOTS + bs * 128 + d];
  float m1 = waveReduceSum(h == 0 ? x : 0.f);
  float m2 = waveReduceSum(h == 0 ? x * x : 0.f);
  if (lane == 0) { S.red[w] = m1; S.red2[w] = m2; }
  __syncthreads();
  float mean = (S.red[0] + S.red[1] + S.red[2] + S.red[3]) * (1.f / 128.f);
  float var = (S.red2[0] + S.red2[1] + S.red2[2] + S.red2[3]) * (1.f / 128.f) - mean * mean;
  if (h == 0) S.yl[d] = (x - mean) * rsqrtf(var + LN_EPS_) * lnsg[d] + lnsb[d];
  __syncthreads();
  float q = halfDot(Wq + (size_t)d * 128, S.yl, h);
  q += __shfl_xor(q, 1, 64);
  if (h == 0) S.ql[d] = q;
  __syncthreads();
  float qv = waveReduceSum(h == 0 ? q * f_b2[d] : 0.f);
  if (lane == 0) S.red[w] = qv;
  float qf = halfDot(FW2T + (size_t)d * 128, S.ql, h);
  qf += __shfl_xor(qf, 1, 64);
  __syncthreads();
  if (t == 0) ws[OFF_QB + bs] = (S.red[0] + S.red[1] + S.red[2] + S.red[3]) * SCALE;
  if (h == 0) {
    float sp0 = ws[OFF_SP + bs * 2 + 0], sp1 = ws[OFF_SP + bs * 2 + 1];
    float offd = -(sp0 * ws[OFF_GFD + d * 2 + 0] + sp1 * ws[OFF_GFD + d * 2 + 1]);
    ws[OFF_OQ + (bs * 128 + d) * 2 + 0] = offd;
    ws[OFF_OQ + (bs * 128 + d) * 2 + 1] = qf * SCALE;
  }
}

// grid: 1024 GEMM blocks (mat = blk>>9, rb = blk&511, 64 rows each) + 64 doQ
__global__ __launch_bounds__(256) void kBaseQ(const float* __restrict__ Wq,
                                              const float* __restrict__ f_b2,
                                              const float* __restrict__ lnsg,
                                              const float* __restrict__ lnsb,
                                              float* __restrict__ ws) {
  __shared__ __align__(16) char smem[17408];
  int blk = blockIdx.x;
  if (blk >= 1024) {      // initial q projection blocks
    doQ(blk - 1024, Wq, f_b2, lnsg, lnsb, ws, *reinterpret_cast<QSm*>(smem));
    return;
  }
  char* ep = smem;
  const ushort_t* ab = (const ushort_t*)(ws + OFF_AB);
  int tid = threadIdx.x, w = tid >> 6, l = tid & 63;
  int lr = l & 15, lg = l >> 4;
  int mat = blk >> 9;
  int rb = blk & 511;                 // 0..511 (64-row block index)
  int b = rb >> 6;
  int n0 = (rb & 63) * 64;            // pixel base within batch
  const ushort_t* Wg = (const ushort_t*)(ws + (mat ? OFF_WVB : OFF_WKB));

  short8 afrag[4];
#pragma unroll
  for (int ks = 0; ks < 4; ++ks) {
    size_t row = (size_t)b * 4096 + n0 + w * 16 + lr;
    afrag[ks] = *(const short8*)(ab + row * 128 + ks * 32 + lg * 8);
  }
  float gf0a[8], gf1a[8], cba[8];
#pragma unroll
  for (int ct = 0; ct < 8; ++ct) {
    int c = ct * 16 + lr;
    gf0a[ct] = ws[OFF_GFD + c * 2 + 0];
    gf1a[ct] = ws[OFF_GFD + c * 2 + 1];
    cba[ct]  = ws[OFF_CB + c];
  }
  f32x4 acc[8];
#pragma unroll
  for (int ct = 0; ct < 8; ++ct) acc[ct] = (f32x4){0.f, 0.f, 0.f, 0.f};
#pragma unroll 2
  for (int ct = 0; ct < 8; ++ct) {
    short8 bfr[4];
#pragma unroll
    for (int ks = 0; ks < 4; ++ks)
      bfr[ks] = *(const short8*)(Wg + (ct * 16 + lr) * 128 + ks * 32 + lg * 8);
#pragma unroll
    for (int ks = 0; ks < 4; ++ks)
      acc[ct] = __builtin_amdgcn_mfma_f32_16x16x32_bf16(afrag[ks], bfr[ks], acc[ct], 0, 0, 0);
  }
#pragma unroll
  for (int ct = 0; ct < 8; ++ct) {
    int c = ct * 16 + lr;
    ushort_t pk[4];
#pragma unroll
    for (int r = 0; r < 4; ++r) {
      int nl = w * 16 + lg * 4 + r;
      int n = n0 + nl;
      float gy = -1.f + (float)(n >> 6) * (2.f / 63.f);
      float gx = -1.f + (float)(n & 63) * (2.f / 63.f);
      float o = acc[ct][r] + gy * gf0a[ct] + gx * gf1a[ct] + cba[ct];
      pk[r] = f2bf(o);
    }
    if (mat == 0) {
      int nl0 = w * 16 + lg * 4;
      int byte = (c * 128 + nl0 * 2) ^ ((c & 7) << 4);
      *(uint2*)(ep + byte) = make_uint2(
          (uint_t)pk[0] | ((uint_t)pk[1] << 16),
          (uint_t)pk[2] | ((uint_t)pk[3] << 16));
    } else {
      int nl0 = w * 16 + lg * 4;
#pragma unroll
      for (int r = 0; r < 4; ++r)
        *(ushort_t*)(ep + (nl0 + r) * 272 + c * 2) = pk[r];
    }
  }
  __syncthreads();
  if (mat == 0) {
    uint_t* outK = (uint_t*)(ws + OFF_BKT);
    for (int idx = tid; idx < 1024; idx += 256) {
      int dp = idx >> 4, j = idx & 15;
      int c0 = 2 * dp, c1 = 2 * dp + 1;
      uint2 aA = *(const uint2*)(ep + ((c0 * 128 + j * 8) ^ ((c0 & 7) << 4)));
      uint2 bA = *(const uint2*)(ep + ((c1 * 128 + j * 8) ^ ((c1 & 7) << 4)));
      uint4 o;
      o.x = (aA.x & 0xffffu) | (bA.x << 16);
      o.y = (aA.x >> 16) | (bA.x & 0xffff0000u);
      o.z = (aA.y & 0xffffu) | (bA.y << 16);
      o.w = (aA.y >> 16) | (bA.y & 0xffff0000u);
      *(uint4*)(outK + ((size_t)(b * 64 + dp)) * 4096 + n0 + j * 4) = o;
    }
  } else {
    ushort_t* outV = (ushort_t*)(ws + OFF_BV);
    for (int idx = tid; idx < 1024; idx += 256) {
      int nl = idx >> 4, j = idx & 15;
      uint4 v = *(const uint4*)(ep + nl * 272 + j * 16);
      *(uint4*)(outV + ((size_t)rb * 64 + nl) * 128 + j * 8) = v;
    }
  }
}

// ---------------- fused attention: 4 waves, d-split / i-split, K+V prefetch ----------------
__global__ __launch_bounds__(256) void kAttn(float* __restrict__ ws) {
  __shared__ __align__(16) float OFFl[8][128];
  __shared__ __align__(16) float QFl[8][128];
  __shared__ float tp[64][37];
  __shared__ __align__(16) float al[64][12];
  __shared__ float Ush[4][8][132];
  int b = blockIdx.x >> 6, chunk = blockIdx.x & 63;
  int tid = threadIdx.x, w = tid >> 6, lane = tid & 63;
  int sb = b * 8;
  int n = chunk * 64 + lane;
  // ---- prefetch: all 16 K-loads + all 16 V-loads issued up front ----
  const uint_t* kpp = (const uint_t*)(ws + OFF_BKT) +
                      (size_t)b * 262144 + (size_t)(w * 16) * 4096 + n;
  uint_t karr[16];
#pragma unroll
  for (int dp = 0; dp < 16; ++dp) karr[dp] = kpp[(size_t)dp * 4096];
  int c0 = 2 * lane;
  const ushort_t* vp = (const ushort_t*)(ws + OFF_BV) +
                       ((size_t)(b * 4096 + chunk * 64 + w * 16)) * 128 + c0;
  uint_t varr[16];
#pragma unroll
  for (int i = 0; i < 16; ++i) varr[i] = *(const uint_t*)(vp + (size_t)i * 128);
  for (int f = tid; f < 1024; f += 256) {
    int s = f >> 7, d = f & 127;
    float2 oq = *(const float2*)&ws[OFF_OQ + ((sb + s) * 128 + d) * 2];
    OFFl[s][d] = oq.x;
    QFl[s][d] = oq.y;
  }
  float qbl[8];
#pragma unroll
  for (int s = 0; s < 8; ++s) qbl[s] = ws[OFF_QB + sb + s];
  __syncthreads();

  // phase 1: pixel-per-lane dots over prefetched K
  float t[8];
#pragma unroll
  for (int s = 0; s < 8; ++s) t[s] = 0.f;
#pragma unroll
  for (int dp = 0; dp < 16; ++dp) {
    uint_t v = karr[dp];
    float k0 = bf2f(v & 0xffffu);
    float k1 = bf2f(v >> 16);
    int d0 = w * 32 + 2 * dp;
#pragma unroll
    for (int s = 0; s < 8; ++s) {
      float2 ofp = *(const float2*)&OFFl[s][d0];
      float2 qfp = *(const float2*)&QFl[s][d0];
      t[s] = fmaf(fmaxf(k0 + ofp.x, 0.f), qfp.x, t[s]);
      t[s] = fmaf(fmaxf(k1 + ofp.y, 0.f), qfp.y, t[s]);
    }
  }
#pragma unroll
  for (int s = 0; s < 8; ++s) tp[lane][s * 4 + w] = t[s];
  __syncthreads();
  float a[8], den = 0.f;
#pragma unroll
  for (int s = 0; s < 8; ++s)
    t[s] = tp[lane][s * 4 + 0] + tp[lane][s * 4 + 1] +
           tp[lane][s * 4 + 2] + tp[lane][s * 4 + 3] + qbl[s];
  float mx = t[0];
#pragma unroll
  for (int s = 1; s < 8; ++s) mx = fmaxf(mx, t[s]);
#pragma unroll
  for (int s = 0; s < 8; ++s) { a[s] = __expf(t[s] - mx); den += a[s]; }
  float inv = 1.0f / den;
#pragma unroll
  for (int s = 0; s < 8; ++s) a[s] = fmaf(a[s], inv, EPS_);
  if (w == 0) {
    float gy = -1.f + (float)(n >> 6) * (2.f / 63.f);
    float gx = -1.f + (float)(n & 63) * (2.f / 63.f);
#pragma unroll
    for (int s = 0; s < 8; ++s) al[lane][s] = a[s];
#pragma unroll
    for (int s = 0; s < 8; ++s) {
      float z = waveReduceSum(a[s]);
      float p0 = waveReduceSum(a[s] * gy);
      float p1 = waveReduceSum(a[s] * gx);
      if (lane == 0) {
        ws[OFF_ZP + (b * 64 + chunk) * 8 + s] = z;
        ws[OFF_PP + ((b * 64 + chunk) * 8 + s) * 2 + 0] = p0;
        ws[OFF_PP + ((b * 64 + chunk) * 8 + s) * 2 + 1] = p1;
      }
    }
  }
  __syncthreads();

  // phase 2: channel-pair-per-lane over this wave's 16 pixels (V prefetched)
  float offv0[8], offv1[8];
#pragma unroll
  for (int s = 0; s < 8; ++s) {
    float2 of2 = *(const float2*)&OFFl[s][c0];
    offv0[s] = of2.x;
    offv1[s] = of2.y;
  }
  float Ua0[8], Ua1[8];
#pragma unroll
  for (int s = 0; s < 8; ++s) { Ua0[s] = 0.f; Ua1[s] = 0.f; }
#pragma unroll 4
  for (int i = 0; i < 16; ++i) {
    uint_t vraw = varr[i];
    float v0 = bf2f(vraw & 0xffffu);
    float v1 = bf2f(vraw >> 16);
    int ii = w * 16 + i;
    float4 a0 = *(const float4*)&al[ii][0];
    float4 a1 = *(const float4*)&al[ii][4];
    float asv[8] = {a0.x, a0.y, a0.z, a0.w, a1.x, a1.y, a1.z, a1.w};
#pragma unroll
    for (int s = 0; s < 8; ++s) {
      Ua0[s] = fmaf(asv[s], fmaxf(v0 + offv0[s], 0.f), Ua0[s]);
      Ua1[s] = fmaf(asv[s], fmaxf(v1 + offv1[s], 0.f), Ua1[s]);
    }
  }
#pragma unroll
  for (int s = 0; s < 8; ++s) {
    Ush[w][s][c0] = Ua0[s];
    Ush[w][s][c0 + 1] = Ua1[s];
  }
  __syncthreads();
  for (int f = tid; f < 1024; f += 256) {
    int s = f >> 7, c = f & 127;
    float v = Ush[0][s][c] + Ush[1][s][c] + Ush[2][s][c] + Ush[3][s][c];
    ws[OFF_UP + ((size_t)(b * 64 + chunk) * 8 + s) * 128 + c] = v;
  }
}

// ---------------- fused: finalize + GRU + post-MLP + next-iter q ----------------
__global__ __launch_bounds__(512) void kCQ(
    const float* __restrict__ Wq, const float* __restrict__ f_w2,
    const float* __restrict__ f_b2, const float* __restrict__ wih,
    const float* __restrict__ whh, const float* __restrict__ bih,
    const float* __restrict__ bhh, const float* __restrict__ mw1,
    const float* __restrict__ mb1, const float* __restrict__ mw2,
    const float* __restrict__ mb2, const float* __restrict__ lnpg,
    const float* __restrict__ lnpb, const float* __restrict__ lnsg,
    const float* __restrict__ lnsb, const float* __restrict__ S_r,
    const float* __restrict__ S_s, float* __restrict__ ws,
    float* __restrict__ out, int last) {
  int bs = blockIdx.x;
  int t = threadIdx.x;
  if (bs == 64) {         // only on last iter: S_r / S_s passthrough
    if (t < 256) out[8320 + t] = S_r[t];
    else if (t < 384) out[8576 + t - 256] = S_s[t - 256];
    return;
  }
  int b = bs >> 3, s = bs & 7;
  int w = t >> 6, lane = t & 63;
  int d = t >> 2, h = t & 3;
  __shared__ __align__(16) float ul[128], xl[128], sl[128], yl[128], hml[128];
  __shared__ float red[8], red2[8];
  const float* FW2T = ws + OFF_FW2T;
  float zv = ws[OFF_ZP + (b * 64 + lane) * 8 + s];
  float2 pv = *(const float2*)&ws[OFF_PP + ((size_t)(b * 64 + lane) * 8 + s) * 2];
  float Z = waveReduceSum(zv);
  float P0 = waveReduceSum(pv.x);
  float P1 = waveReduceSum(pv.y);
  float invZ = 1.f / Z, sp0 = P0 * invZ, sp1 = P1 * invZ;
  float u = 0.f;
  const float* up = ws + OFF_UP + ((size_t)(b * 64 + h * 16) * 8 + s) * 128 + d;
#pragma unroll
  for (int ch = 0; ch < 16; ++ch) u += up[(size_t)ch * 1024];
  u = quadSum(u);
  if (h == 0) { ul[d] = u * invZ; sl[d] = ws[OFF_SLOTS + bs * 128 + d]; }
  if (t == 0) {
    ws[OFF_SP + bs * 2 + 0] = sp0;
    ws[OFF_SP + bs * 2 + 1] = sp1;
    if (last) {
      out[8192 + bs * 2 + 0] = sp0;
      out[8192 + bs * 2 + 1] = sp1;
    }
  }
  __syncthreads();
  float xa = quadSum(quarterDot(f_w2 + (size_t)d * 128, ul, h));
  if (h == 0) xl[d] = xa + f_b2[d];
  __syncthreads();
  float ir = quarterDot(wih + (size_t)d * 128, xl, h);
  float iz = quarterDot(wih + (size_t)(128 + d) * 128, xl, h);
  float in_ = quarterDot(wih + (size_t)(256 + d) * 128, xl, h);
  float hr = quarterDot(whh + (size_t)d * 128, sl, h);
  float hz = quarterDot(whh + (size_t)(128 + d) * 128, sl, h);
  float hn = quarterDot(whh + (size_t)(256 + d) * 128, sl, h);
  ir = quadSum(ir); iz = quadSum(iz); in_ = quadSum(in_);
  hr = quadSum(hr); hz = quadSum(hz); hn = quadSum(hn);
  float hnew = 0.f;
  if (h == 0) {
    float rg = 1.f / (1.f + __expf(-(ir + bih[d] + hr + bhh[d])));
    float zg = 1.f / (1.f + __expf(-(iz + bih[128 + d] + hz + bhh[128 + d])));
    float ng = tanhf(in_ + bih[256 + d] + rg * (hn + bhh[256 + d]));
    hnew = (1.f - zg) * ng + zg * sl[d];
  }
  float m1 = waveReduceSum(h == 0 ? hnew : 0.f);
  float m2 = waveReduceSum(h == 0 ? hnew * hnew : 0.f);
  if (lane == 0) { red[w] = m1; red2[w] = m2; }
  __syncthreads();
  float mean = 0.f, var = 0.f;
#pragma unroll
  for (int i = 0; i < 8; ++i) { mean += red[i]; var += red2[i]; }
  mean *= (1.f / 128.f);
  var = var * (1.f / 128.f) - mean * mean;
  if (h == 0) yl[d] = (hnew - mean) * rsqrtf(var + LN_EPS_) * lnpg[d] + lnpb[d];
  __syncthreads();
  float hm = quadSum(quarterDot(mw1 + (size_t)d * 128, yl, h));
  if (h == 0) hml[d] = fmaxf(hm + mb1[d], 0.f);
  __syncthreads();
  float oa = quadSum(quarterDot(mw2 + (size_t)d * 128, hml, h));
  float o = 0.f;
  if (h == 0) {
    o = hnew + mb2[d] + oa;
    ws[OFF_SLOTS + bs * 128 + d] = o;
    if (last) out[bs * 128 + d] = o;
  }
  float n1 = waveReduceSum(h == 0 ? o : 0.f);
  float n2 = waveReduceSum(h == 0 ? o * o : 0.f);
  if (lane == 0) { red[w] = n1; red2[w] = n2; }
  __syncthreads();
  float mean2 = 0.f, var2 = 0.f;
#pragma unroll
  for (int i = 0; i < 8; ++i) { mean2 += red[i]; var2 += red2[i]; }
  mean2 *= (1.f / 128.f);
  var2 = var2 * (1.f / 128.f) - mean2 * mean2;
  if (h == 0) yl[d] = (o - mean2) * rsqrtf(var2 + LN_EPS_) * lnsg[d] + lnsb[d];
  __syncthreads();
  float q = quadSum(quarterDot(Wq + (size_t)d * 128, yl, h));
  if (h == 0) xl[d] = q;
  __syncthreads();
  float qv = waveReduceSum(h == 0 ? q * f_b2[d] : 0.f);
  if (lane == 0) red[w] = qv;
  float qf = quadSum(quarterDot(FW2T + (size_t)d * 128, xl, h));
  __syncthreads();
  if (t == 0) {
    float qb = 0.f;
#pragma unroll
    for (int i = 0; i < 8; ++i) qb += red[i];
    ws[OFF_QB + bs] = qb * SCALE;
  }
  if (h == 0) {
    float offd = -(sp0 * ws[OFF_GFD + d * 2 + 0] + sp1 * ws[OFF_GFD + d * 2 + 1]);
    ws[OFF_OQ + (bs * 128 + d) * 2 + 0] = offd;
    ws[OFF_OQ + (bs * 128 + d) * 2 + 1] = qf * SCALE;
  }
}

extern "C" void kernel_launch(void* const* d_in, const int* in_sizes, int n_in,
                              void* d_out, int out_size, void* d_ws, size_t ws_size,
                              hipStream_t stream) {
  const float* inputs     = (const float*)d_in[0];
  const float* slots_init = (const float*)d_in[1];
  const float* S_p0       = (const float*)d_in[2];
  const float* S_s        = (const float*)d_in[3];
  const float* S_r        = (const float*)d_in[4];
  const float* Wq   = (const float*)d_in[5];
  const float* Wk   = (const float*)d_in[6];
  const float* Wv   = (const float*)d_in[7];
  const float* g_w  = (const float*)d_in[8];
  const float* g_b  = (const float*)d_in[9];
  const float* f_w1 = (const float*)d_in[10];
  const float* f_b1 = (const float*)d_in[11];
  const float* f_w2 = (const float*)d_in[12];
  const float* f_b2 = (const float*)d_in[13];
  const float* gwih = (const float*)d_in[14];
  const float* gwhh = (const float*)d_in[15];
  const float* gbih = (const float*)d_in[16];
  const float* gbhh = (const float*)d_in[17];
  const float* mw1  = (const float*)d_in[18];
  const float* mb1  = (const float*)d_in[19];
  const float* mw2  = (const float*)d_in[20];
  const float* mb2  = (const float*)d_in[21];
  const float* lnsg = (const float*)d_in[22];
  const float* lnsb = (const float*)d_in[23];
  const float* lnpg = (const float*)d_in[24];
  const float* lnpb = (const float*)d_in[25];
  float* ws  = (float*)d_ws;
  float* out = (float*)d_out;

  kFold<<<392, 256, 0, stream>>>(f_w1, Wk, Wv, g_w, g_b, f_b1, f_w2,
                                 slots_init, S_p0, inputs, ws);
  kBaseQ<<<1088, 256, 0, stream>>>(Wq, f_b2, lnsg, lnsb, ws);
  for (int it = 0; it < 3; ++it) {
    int last = (it == 2);
    kAttn<<<512, 256, 0, stream>>>(ws);
    kCQ<<<64 + last, 512, 0, stream>>>(Wq, f_w2, f_b2, gwih, gwhh, gbih, gbhh,
                                       mw1, mb1, mw2, mb2, lnpg, lnpb,
                                       lnsg, lnsb, S_r, S_s, ws, out, last);
  }
}

// Round 15
// 156.969 us; speedup vs baseline: 1.3593x; 1.0054x over previous
//
#include <hip/hip_runtime.h>
#include <cstdint>
#include <cstddef>

#define SCALE  0.08838834764831845f   // 128^-0.5
#define EPS_   1e-8f
#define LN_EPS_ 1e-5f

typedef unsigned short ushort_t;
typedef unsigned int uint_t;
typedef __attribute__((ext_vector_type(8))) short short8;
typedef __attribute__((ext_vector_type(4))) float f32x4;

// ---------------- workspace layout (float offsets), 23.3 MB ----------------
constexpr int OFF_GFD   = 0;        // 256   (f_w1@g_w)/DELTA  [h][2]
constexpr int OFF_CB    = 256;      // 128   f_w1@g_b + f_b1
constexpr int OFF_QB    = 384;      // 64
constexpr int OFF_SP    = 448;      // 128
constexpr int OFF_OQ    = 576;      // 16384 interleaved (off, qf*scale)
constexpr int OFF_SLOTS = 16960;    // 8192
constexpr int OFF_ZP    = 25152;    // 4096   [b][64][8]
constexpr int OFF_PP    = 29248;    // 8192   [b][64][8][2]
constexpr int OFF_UP    = 37440;    // 524288 [b][64][8][128]
constexpr int OFF_WKB   = 561728;   // bf16 [128][128] = 8192 float-slots
constexpr int OFF_WVB   = 569920;   // 8192
constexpr int OFF_FW2T  = 578112;   // f32 f_w2^T 16384
constexpr int OFF_BKT   = 594496;   // uint [b][64 dp][4096 n] = 2097152 float-slots
constexpr int OFF_BV    = 2691648;  // bf16 [b][4096][128] = 2097152 float-slots
constexpr int OFF_AB    = 4788800;  // bf16 inputs [32768][128] = 1048576 float-slots
// end: 5837376 floats

__device__ __forceinline__ float waveReduceSum(float v) {
#pragma unroll
  for (int m = 1; m < 64; m <<= 1) v += __shfl_xor(v, m, 64);
  return v;
}
__device__ __forceinline__ float bf2f(uint_t u) { return __uint_as_float(u << 16); }
__device__ __forceinline__ ushort_t f2bf(float f) {
  uint_t u = __float_as_uint(f);
  return (ushort_t)((u + 0x7fffu + ((u >> 16) & 1u)) >> 16);
}

// half-row dot (e-range [h*64, h*64+64)), 16 independent float4 loads
__device__ __forceinline__ float halfDot(const float* __restrict__ Wrow,
                                         const float* xv, int h) {
  const float4* wr = (const float4*)Wrow + h * 16;
  const float4* xr = (const float4*)xv + h * 16;
  float4 a = {0.f, 0.f, 0.f, 0.f};
#pragma unroll
  for (int i = 0; i < 16; ++i) {
    float4 wv = wr[i], xq = xr[i];
    a.x = fmaf(wv.x, xq.x, a.x);
    a.y = fmaf(wv.y, xq.y, a.y);
    a.z = fmaf(wv.z, xq.z, a.z);
    a.w = fmaf(wv.w, xq.w, a.w);
  }
  return (a.x + a.y) + (a.z + a.w);
}

// quarter-row dot (e-range [h*32, h*32+32)), 8 independent float4 loads
__device__ __forceinline__ float quarterDot(const float* __restrict__ Wrow,
                                            const float* xv, int h) {
  const float4* wr = (const float4*)Wrow + h * 8;
  const float4* xr = (const float4*)xv + h * 8;
  float4 a = {0.f, 0.f, 0.f, 0.f};
#pragma unroll
  for (int i = 0; i < 8; ++i) {
    float4 wv = wr[i], xq = xr[i];
    a.x = fmaf(wv.x, xq.x, a.x);
    a.y = fmaf(wv.y, xq.y, a.y);
    a.z = fmaf(wv.z, xq.z, a.z);
    a.w = fmaf(wv.w, xq.w, a.w);
  }
  return (a.x + a.y) + (a.z + a.w);
}
__device__ __forceinline__ float quadSum(float v) {
  v += __shfl_xor(v, 1, 64);
  v += __shfl_xor(v, 2, 64);
  return v;
}

// ---------------- fold weights + init copies + input cast + SrSs out ----------------
__global__ __launch_bounds__(256) void kFold(
    const float* __restrict__ f_w1, const float* __restrict__ Wk,
    const float* __restrict__ Wv, const float* __restrict__ g_w,
    const float* __restrict__ g_b, const float* __restrict__ f_b1,
    const float* __restrict__ f_w2, const float* __restrict__ slots_init,
    const float* __restrict__ S_p0, const float* __restrict__ inputs,
    const float* __restrict__ S_r, const float* __restrict__ S_s,
    float* __restrict__ ws, float* __restrict__ out) {
  int blk = blockIdx.x, tid = threadIdx.x;
  if (blk < 128) {
    int isV = blk >> 6;
    int idx = (blk & 63) * 256 + tid;           // 0..16383  (h*128+e)
    int h = idx >> 7, e = idx & 127;
    const float* Wm = isV ? Wv : Wk;
    float a = 0.f;
#pragma unroll 4
    for (int d = 0; d < 128; ++d) a = fmaf(f_w1[h * 128 + d], Wm[d * 128 + e], a);
    ((ushort_t*)(ws + (isV ? OFF_WVB : OFF_WKB)))[idx] = f2bf(a);
  } else if (blk == 128) {
    int h = tid >> 1, c = tid & 1;
    float a = 0.f;
    for (int d = 0; d < 128; ++d) a = fmaf(f_w1[h * 128 + d], g_w[d * 2 + c], a);
    ws[OFF_GFD + tid] = a * 0.2f;               // /DELTA (DELTA=5)
  } else if (blk == 129) {
    if (tid < 128) {
      float a = f_b1[tid];
      for (int d = 0; d < 128; ++d) a = fmaf(f_w1[tid * 128 + d], g_b[d], a);
      ws[OFF_CB + tid] = a;
    }
  } else if (blk == 130) {
    for (int i = tid; i < 16384; i += 256)
      ws[OFF_FW2T + (i & 127) * 128 + (i >> 7)] = f_w2[i];
  } else if (blk < 135) {
    int base = (blk - 131) * 2048 + tid * 8;    // slots copy, 8 floats/thread
    float4 a = *(const float4*)&slots_init[base];
    float4 b = *(const float4*)&slots_init[base + 4];
    *(float4*)&ws[OFF_SLOTS + base] = a;
    *(float4*)&ws[OFF_SLOTS + base + 4] = b;
  } else if (blk == 135) {
    if (tid < 128) ws[OFF_SP + tid] = S_p0[tid];
    else if (tid < 256) out[8576 + tid - 128] = S_s[tid - 128];
  } else if (blk == 136) {
    out[8320 + tid] = S_r[tid];
  } else {
    // input cast: blocks 137..392, 8 floats per thread
    int idx = (blk - 137) * 256 + tid;          // 0..65535
    const float4* src = (const float4*)(inputs + (size_t)idx * 8);
    float4 a = src[0], b = src[1];
    uint_t p0 = (uint_t)f2bf(a.x) | ((uint_t)f2bf(a.y) << 16);
    uint_t p1 = (uint_t)f2bf(a.z) | ((uint_t)f2bf(a.w) << 16);
    uint_t p2 = (uint_t)f2bf(b.x) | ((uint_t)f2bf(b.y) << 16);
    uint_t p3 = (uint_t)f2bf(b.z) | ((uint_t)f2bf(b.w) << 16);
    ((uint4*)((ushort_t*)(ws + OFF_AB)))[idx] = make_uint4(p0, p1, p2, p3);
  }
}

// ---------------- MFMA base GEMMs (64-row blocks) + initial q ----------------
struct QSm { float yl[128]; float ql[128]; float red[4]; float red2[4]; };

__device__ void doQ(int bs, const float* __restrict__ Wq,
                    const float* __restrict__ f_b2,
                    const float* __restrict__ lnsg,
                    const float* __restrict__ lnsb,
                    float* __restrict__ ws, QSm& S) {
  int t = threadIdx.x, w = t >> 6, lane = t & 63;
  int d = w * 32 + (lane >> 1), h = lane & 1;
  const float* FW2T = ws + OFF_FW2T;
  float x = ws[OFF_SLOTS + bs * 128 + d];
  float m1 = waveReduceSum(h == 0 ? x : 0.f);
  float m2 = waveReduceSum(h == 0 ? x * x : 0.f);
  if (lane == 0) { S.red[w] = m1; S.red2[w] = m2; }
  __syncthreads();
  float mean = (S.red[0] + S.red[1] + S.red[2] + S.red[3]) * (1.f / 128.f);
  float var = (S.red2[0] + S.red2[1] + S.red2[2] + S.red2[3]) * (1.f / 128.f) - mean * mean;
  if (h == 0) S.yl[d] = (x - mean) * rsqrtf(var + LN_EPS_) * lnsg[d] + lnsb[d];
  __syncthreads();
  float q = halfDot(Wq + (size_t)d * 128, S.yl, h);
  q += __shfl_xor(q, 1, 64);
  if (h == 0) S.ql[d] = q;
  __syncthreads();
  float qv = waveReduceSum(h == 0 ? q * f_b2[d] : 0.f);
  if (lane == 0) S.red[w] = qv;
  float qf = halfDot(FW2T + (size_t)d * 128, S.ql, h);
  qf += __shfl_xor(qf, 1, 64);
  __syncthreads();
  if (t == 0) ws[OFF_QB + bs] = (S.red[0] + S.red[1] + S.red[2] + S.red[3]) * SCALE;
  if (h == 0) {
    float sp0 = ws[OFF_SP + bs * 2 + 0], sp1 = ws[OFF_SP + bs * 2 + 1];
    float offd = -(sp0 * ws[OFF_GFD + d * 2 + 0] + sp1 * ws[OFF_GFD + d * 2 + 1]);
    ws[OFF_OQ + (bs * 128 + d) * 2 + 0] = offd;
    ws[OFF_OQ + (bs * 128 + d) * 2 + 1] = qf * SCALE;
  }
}

// grid: 1024 GEMM blocks (mat = blk>>9, rb = blk&511, 64 rows each) + 64 doQ
__global__ __launch_bounds__(256) void kBaseQ(const float* __restrict__ Wq,
                                              const float* __restrict__ f_b2,
                                              const float* __restrict__ lnsg,
                                              const float* __restrict__ lnsb,
                                              float* __restrict__ ws) {
  __shared__ __align__(16) char smem[17408];
  int blk = blockIdx.x;
  if (blk >= 1024) {      // initial q projection blocks
    doQ(blk - 1024, Wq, f_b2, lnsg, lnsb, ws, *reinterpret_cast<QSm*>(smem));
    return;
  }
  char* ep = smem;
  const ushort_t* ab = (const ushort_t*)(ws + OFF_AB);
  int tid = threadIdx.x, w = tid >> 6, l = tid & 63;
  int lr = l & 15, lg = l >> 4;
  int mat = blk >> 9;
  int rb = blk & 511;                 // 0..511 (64-row block index)
  int b = rb >> 6;
  int n0 = (rb & 63) * 64;            // pixel base within batch
  const ushort_t* Wg = (const ushort_t*)(ws + (mat ? OFF_WVB : OFF_WKB));

  short8 afrag[4];
#pragma unroll
  for (int ks = 0; ks < 4; ++ks) {
    size_t row = (size_t)b * 4096 + n0 + w * 16 + lr;
    afrag[ks] = *(const short8*)(ab + row * 128 + ks * 32 + lg * 8);
  }
  float gf0a[8], gf1a[8], cba[8];
#pragma unroll
  for (int ct = 0; ct < 8; ++ct) {
    int c = ct * 16 + lr;
    gf0a[ct] = ws[OFF_GFD + c * 2 + 0];
    gf1a[ct] = ws[OFF_GFD + c * 2 + 1];
    cba[ct]  = ws[OFF_CB + c];
  }
  f32x4 acc[8];
#pragma unroll
  for (int ct = 0; ct < 8; ++ct) acc[ct] = (f32x4){0.f, 0.f, 0.f, 0.f};
#pragma unroll 2
  for (int ct = 0; ct < 8; ++ct) {
    short8 bfr[4];
#pragma unroll
    for (int ks = 0; ks < 4; ++ks)
      bfr[ks] = *(const short8*)(Wg + (ct * 16 + lr) * 128 + ks * 32 + lg * 8);
#pragma unroll
    for (int ks = 0; ks < 4; ++ks)
      acc[ct] = __builtin_amdgcn_mfma_f32_16x16x32_bf16(afrag[ks], bfr[ks], acc[ct], 0, 0, 0);
  }
#pragma unroll
  for (int ct = 0; ct < 8; ++ct) {
    int c = ct * 16 + lr;
    ushort_t pk[4];
#pragma unroll
    for (int r = 0; r < 4; ++r) {
      int nl = w * 16 + lg * 4 + r;
      int n = n0 + nl;
      float gy = -1.f + (float)(n >> 6) * (2.f / 63.f);
      float gx = -1.f + (float)(n & 63) * (2.f / 63.f);
      float o = acc[ct][r] + gy * gf0a[ct] + gx * gf1a[ct] + cba[ct];
      pk[r] = f2bf(o);
    }
    if (mat == 0) {
      int nl0 = w * 16 + lg * 4;
      int byte = (c * 128 + nl0 * 2) ^ ((c & 7) << 4);
      *(uint2*)(ep + byte) = make_uint2(
          (uint_t)pk[0] | ((uint_t)pk[1] << 16),
          (uint_t)pk[2] | ((uint_t)pk[3] << 16));
    } else {
      int nl0 = w * 16 + lg * 4;
#pragma unroll
      for (int r = 0; r < 4; ++r)
        *(ushort_t*)(ep + (nl0 + r) * 272 + c * 2) = pk[r];
    }
  }
  __syncthreads();
  if (mat == 0) {
    uint_t* outK = (uint_t*)(ws + OFF_BKT);
    for (int idx = tid; idx < 1024; idx += 256) {
      int dp = idx >> 4, j = idx & 15;
      int c0 = 2 * dp, c1 = 2 * dp + 1;
      uint2 aA = *(const uint2*)(ep + ((c0 * 128 + j * 8) ^ ((c0 & 7) << 4)));
      uint2 bA = *(const uint2*)(ep + ((c1 * 128 + j * 8) ^ ((c1 & 7) << 4)));
      uint4 o;
      o.x = (aA.x & 0xffffu) | (bA.x << 16);
      o.y = (aA.x >> 16) | (bA.x & 0xffff0000u);
      o.z = (aA.y & 0xffffu) | (bA.y << 16);
      o.w = (aA.y >> 16) | (bA.y & 0xffff0000u);
      *(uint4*)(outK + ((size_t)(b * 64 + dp)) * 4096 + n0 + j * 4) = o;
    }
  } else {
    ushort_t* outV = (ushort_t*)(ws + OFF_BV);
    for (int idx = tid; idx < 1024; idx += 256) {
      int nl = idx >> 4, j = idx & 15;
      uint4 v = *(const uint4*)(ep + nl * 272 + j * 16);
      *(uint4*)(outV + ((size_t)rb * 64 + nl) * 128 + j * 8) = v;
    }
  }
}

// ---------------- fused attention: 4 waves, K+V prefetch, distributed Z/P ----------------
__global__ __launch_bounds__(256) void kAttn(float* __restrict__ ws) {
  __shared__ __align__(16) float OFFl[8][128];
  __shared__ __align__(16) float QFl[8][128];
  __shared__ float tp[64][37];
  __shared__ __align__(16) float al[64][12];
  __shared__ float Ush[4][8][132];
  int b = blockIdx.x >> 6, chunk = blockIdx.x & 63;
  int tid = threadIdx.x, w = tid >> 6, lane = tid & 63;
  int sb = b * 8;
  int n = chunk * 64 + lane;
  // prefetch: all 16 K-loads + all 16 V-loads issued up front
  const uint_t* kpp = (const uint_t*)(ws + OFF_BKT) +
                      (size_t)b * 262144 + (size_t)(w * 16) * 4096 + n;
  uint_t karr[16];
#pragma unroll
  for (int dp = 0; dp < 16; ++dp) karr[dp] = kpp[(size_t)dp * 4096];
  int c0 = 2 * lane;
  const ushort_t* vp = (const ushort_t*)(ws + OFF_BV) +
                       ((size_t)(b * 4096 + chunk * 64 + w * 16)) * 128 + c0;
  uint_t varr[16];
#pragma unroll
  for (int i = 0; i < 16; ++i) varr[i] = *(const uint_t*)(vp + (size_t)i * 128);
  for (int f = tid; f < 1024; f += 256) {
    int s = f >> 7, d = f & 127;
    float2 oq = *(const float2*)&ws[OFF_OQ + ((sb + s) * 128 + d) * 2];
    OFFl[s][d] = oq.x;
    QFl[s][d] = oq.y;
  }
  float qbl[8];
#pragma unroll
  for (int s = 0; s < 8; ++s) qbl[s] = ws[OFF_QB + sb + s];
  __syncthreads();

  // phase 1: pixel-per-lane dots over prefetched K
  float t[8];
#pragma unroll
  for (int s = 0; s < 8; ++s) t[s] = 0.f;
#pragma unroll
  for (int dp = 0; dp < 16; ++dp) {
    uint_t v = karr[dp];
    float k0 = bf2f(v & 0xffffu);
    float k1 = bf2f(v >> 16);
    int d0 = w * 32 + 2 * dp;
#pragma unroll
    for (int s = 0; s < 8; ++s) {
      float2 ofp = *(const float2*)&OFFl[s][d0];
      float2 qfp = *(const float2*)&QFl[s][d0];
      t[s] = fmaf(fmaxf(k0 + ofp.x, 0.f), qfp.x, t[s]);
      t[s] = fmaf(fmaxf(k1 + ofp.y, 0.f), qfp.y, t[s]);
    }
  }
#pragma unroll
  for (int s = 0; s < 8; ++s) tp[lane][s * 4 + w] = t[s];
  __syncthreads();
  float a[8], den = 0.f;
#pragma unroll
  for (int s = 0; s < 8; ++s)
    t[s] = tp[lane][s * 4 + 0] + tp[lane][s * 4 + 1] +
           tp[lane][s * 4 + 2] + tp[lane][s * 4 + 3] + qbl[s];
  float mx = t[0];
#pragma unroll
  for (int s = 1; s < 8; ++s) mx = fmaxf(mx, t[s]);
#pragma unroll
  for (int s = 0; s < 8; ++s) { a[s] = __expf(t[s] - mx); den += a[s]; }
  float inv = 1.0f / den;
#pragma unroll
  for (int s = 0; s < 8; ++s) a[s] = fmaf(a[s], inv, EPS_);
  // distributed Z/P: every wave holds identical a[]; wave w reduces slots 2w,2w+1
  {
    float gy = -1.f + (float)(n >> 6) * (2.f / 63.f);
    float gx = -1.f + (float)(n & 63) * (2.f / 63.f);
    if (w == 0) {
#pragma unroll
      for (int s = 0; s < 8; ++s) al[lane][s] = a[s];
    }
#pragma unroll
    for (int k = 0; k < 2; ++k) {
      int s = w * 2 + k;
      float z = waveReduceSum(a[s]);
      float p0 = waveReduceSum(a[s] * gy);
      float p1 = waveReduceSum(a[s] * gx);
      if (lane == 0) {
        ws[OFF_ZP + (b * 64 + chunk) * 8 + s] = z;
        ws[OFF_PP + ((b * 64 + chunk) * 8 + s) * 2 + 0] = p0;
        ws[OFF_PP + ((b * 64 + chunk) * 8 + s) * 2 + 1] = p1;
      }
    }
  }
  __syncthreads();

  // phase 2: channel-pair-per-lane over this wave's 16 pixels (V prefetched)
  float offv0[8], offv1[8];
#pragma unroll
  for (int s = 0; s < 8; ++s) {
    float2 of2 = *(const float2*)&OFFl[s][c0];
    offv0[s] = of2.x;
    offv1[s] = of2.y;
  }
  float Ua0[8], Ua1[8];
#pragma unroll
  for (int s = 0; s < 8; ++s) { Ua0[s] = 0.f; Ua1[s] = 0.f; }
#pragma unroll 4
  for (int i = 0; i < 16; ++i) {
    uint_t vraw = varr[i];
    float v0 = bf2f(vraw & 0xffffu);
    float v1 = bf2f(vraw >> 16);
    int ii = w * 16 + i;
    float4 a0 = *(const float4*)&al[ii][0];
    float4 a1 = *(const float4*)&al[ii][4];
    float asv[8] = {a0.x, a0.y, a0.z, a0.w, a1.x, a1.y, a1.z, a1.w};
#pragma unroll
    for (int s = 0; s < 8; ++s) {
      Ua0[s] = fmaf(asv[s], fmaxf(v0 + offv0[s], 0.f), Ua0[s]);
      Ua1[s] = fmaf(asv[s], fmaxf(v1 + offv1[s], 0.f), Ua1[s]);
    }
  }
#pragma unroll
  for (int s = 0; s < 8; ++s) {
    Ush[w][s][c0] = Ua0[s];
    Ush[w][s][c0 + 1] = Ua1[s];
  }
  __syncthreads();
  for (int f = tid; f < 1024; f += 256) {
    int s = f >> 7, c = f & 127;
    float v = Ush[0][s][c] + Ush[1][s][c] + Ush[2][s][c] + Ush[3][s][c];
    ws[OFF_UP + ((size_t)(b * 64 + chunk) * 8 + s) * 128 + c] = v;
  }
}

// ---------------- fused: finalize + GRU + post-MLP + next-iter q ----------------
__global__ __launch_bounds__(512) void kCQ(
    const float* __restrict__ Wq, const float* __restrict__ f_w2,
    const float* __restrict__ f_b2, const float* __restrict__ wih,
    const float* __restrict__ whh, const float* __restrict__ bih,
    const float* __restrict__ bhh, const float* __restrict__ mw1,
    const float* __restrict__ mb1, const float* __restrict__ mw2,
    const float* __restrict__ mb2, const float* __restrict__ lnpg,
    const float* __restrict__ lnpb, const float* __restrict__ lnsg,
    const float* __restrict__ lnsb, float* __restrict__ ws,
    float* __restrict__ out, int last) {
  int bs = blockIdx.x;
  int t = threadIdx.x;
  int b = bs >> 3, s = bs & 7;
  int w = t >> 6, lane = t & 63;
  int d = t >> 2, h = t & 3;
  __shared__ __align__(16) float ul[128], xl[128], sl[128], yl[128], hml[128];
  __shared__ float red[8], red2[8];
  const float* FW2T = ws + OFF_FW2T;
  float zv = ws[OFF_ZP + (b * 64 + lane) * 8 + s];
  float2 pv = *(const float2*)&ws[OFF_PP + ((size_t)(b * 64 + lane) * 8 + s) * 2];
  float Z = waveReduceSum(zv);
  float P0 = waveReduceSum(pv.x);
  float P1 = waveReduceSum(pv.y);
  float invZ = 1.f / Z, sp0 = P0 * invZ, sp1 = P1 * invZ;
  float u = 0.f;
  const float* up = ws + OFF_UP + ((size_t)(b * 64 + h * 16) * 8 + s) * 128 + d;
#pragma unroll
  for (int ch = 0; ch < 16; ++ch) u += up[(size_t)ch * 1024];
  u = quadSum(u);
  if (h == 0) { ul[d] = u * invZ; sl[d] = ws[OFF_SLOTS + bs * 128 + d]; }
  if (t == 0) {
    ws[OFF_SP + bs * 2 + 0] = sp0;
    ws[OFF_SP + bs * 2 + 1] = sp1;
    if (last) {
      out[8192 + bs * 2 + 0] = sp0;
      out[8192 + bs * 2 + 1] = sp1;
    }
  }
  __syncthreads();
  float xa = quadSum(quarterDot(f_w2 + (size_t)d * 128, ul, h));
  if (h == 0) xl[d] = xa + f_b2[d];
  __syncthreads();
  float ir = quarterDot(wih + (size_t)d * 128, xl, h);
  float iz = quarterDot(wih + (size_t)(128 + d) * 128, xl, h);
  float in_ = quarterDot(wih + (size_t)(256 + d) * 128, xl, h);
  float hr = quarterDot(whh + (size_t)d * 128, sl, h);
  float hz = quarterDot(whh + (size_t)(128 + d) * 128, sl, h);
  float hn = quarterDot(whh + (size_t)(256 + d) * 128, sl, h);
  ir = quadSum(ir); iz = quadSum(iz); in_ = quadSum(in_);
  hr = quadSum(hr); hz = quadSum(hz); hn = quadSum(hn);
  float hnew = 0.f;
  if (h == 0) {
    float rg = 1.f / (1.f + __expf(-(ir + bih[d] + hr + bhh[d])));
    float zg = 1.f / (1.f + __expf(-(iz + bih[128 + d] + hz + bhh[128 + d])));
    float ng = tanhf(in_ + bih[256 + d] + rg * (hn + bhh[256 + d]));
    hnew = (1.f - zg) * ng + zg * sl[d];
  }
  float m1 = waveReduceSum(h == 0 ? hnew : 0.f);
  float m2 = waveReduceSum(h == 0 ? hnew * hnew : 0.f);
  if (lane == 0) { red[w] = m1; red2[w] = m2; }
  __syncthreads();
  float mean = 0.f, var = 0.f;
#pragma unroll
  for (int i = 0; i < 8; ++i) { mean += red[i]; var += red2[i]; }
  mean *= (1.f / 128.f);
  var = var * (1.f / 128.f) - mean * mean;
  if (h == 0) yl[d] = (hnew - mean) * rsqrtf(var + LN_EPS_) * lnpg[d] + lnpb[d];
  __syncthreads();
  float hm = quadSum(quarterDot(mw1 + (size_t)d * 128, yl, h));
  if (h == 0) hml[d] = fmaxf(hm + mb1[d], 0.f);
  __syncthreads();
  float oa = quadSum(quarterDot(mw2 + (size_t)d * 128, hml, h));
  float o = 0.f;
  if (h == 0) {
    o = hnew + mb2[d] + oa;
    ws[OFF_SLOTS + bs * 128 + d] = o;
    if (last) out[bs * 128 + d] = o;
  }
  float n1 = waveReduceSum(h == 0 ? o : 0.f);
  float n2 = waveReduceSum(h == 0 ? o * o : 0.f);
  if (lane == 0) { red[w] = n1; red2[w] = n2; }
  __syncthreads();
  float mean2 = 0.f, var2 = 0.f;
#pragma unroll
  for (int i = 0; i < 8; ++i) { mean2 += red[i]; var2 += red2[i]; }
  mean2 *= (1.f / 128.f);
  var2 = var2 * (1.f / 128.f) - mean2 * mean2;
  if (h == 0) yl[d] = (o - mean2) * rsqrtf(var2 + LN_EPS_) * lnsg[d] + lnsb[d];
  __syncthreads();
  float q = quadSum(quarterDot(Wq + (size_t)d * 128, yl, h));
  if (h == 0) xl[d] = q;
  __syncthreads();
  float qv = waveReduceSum(h == 0 ? q * f_b2[d] : 0.f);
  if (lane == 0) red[w] = qv;
  float qf = quadSum(quarterDot(FW2T + (size_t)d * 128, xl, h));
  __syncthreads();
  if (t == 0) {
    float qb = 0.f;
#pragma unroll
    for (int i = 0; i < 8; ++i) qb += red[i];
    ws[OFF_QB + bs] = qb * SCALE;
  }
  if (h == 0) {
    float offd = -(sp0 * ws[OFF_GFD + d * 2 + 0] + sp1 * ws[OFF_GFD + d * 2 + 1]);
    ws[OFF_OQ + (bs * 128 + d) * 2 + 0] = offd;
    ws[OFF_OQ + (bs * 128 + d) * 2 + 1] = qf * SCALE;
  }
}

extern "C" void kernel_launch(void* const* d_in, const int* in_sizes, int n_in,
                              void* d_out, int out_size, void* d_ws, size_t ws_size,
                              hipStream_t stream) {
  const float* inputs     = (const float*)d_in[0];
  const float* slots_init = (const float*)d_in[1];
  const float* S_p0       = (const float*)d_in[2];
  const float* S_s        = (const float*)d_in[3];
  const float* S_r        = (const float*)d_in[4];
  const float* Wq   = (const float*)d_in[5];
  const float* Wk   = (const float*)d_in[6];
  const float* Wv   = (const float*)d_in[7];
  const float* g_w  = (const float*)d_in[8];
  const float* g_b  = (const float*)d_in[9];
  const float* f_w1 = (const float*)d_in[10];
  const float* f_b1 = (const float*)d_in[11];
  const float* f_w2 = (const float*)d_in[12];
  const float* f_b2 = (const float*)d_in[13];
  const float* gwih = (const float*)d_in[14];
  const float* gwhh = (const float*)d_in[15];
  const float* gbih = (const float*)d_in[16];
  const float* gbhh = (const float*)d_in[17];
  const float* mw1  = (const float*)d_in[18];
  const float* mb1  = (const float*)d_in[19];
  const float* mw2  = (const float*)d_in[20];
  const float* mb2  = (const float*)d_in[21];
  const float* lnsg = (const float*)d_in[22];
  const float* lnsb = (const float*)d_in[23];
  const float* lnpg = (const float*)d_in[24];
  const float* lnpb = (const float*)d_in[25];
  float* ws  = (float*)d_ws;
  float* out = (float*)d_out;

  kFold<<<393, 256, 0, stream>>>(f_w1, Wk, Wv, g_w, g_b, f_b1, f_w2,
                                 slots_init, S_p0, inputs, S_r, S_s, ws, out);
  kBaseQ<<<1088, 256, 0, stream>>>(Wq, f_b2, lnsg, lnsb, ws);
  for (int it = 0; it < 3; ++it) {
    int last = (it == 2);
    kAttn<<<512, 256, 0, stream>>>(ws);
    kCQ<<<64, 512, 0, stream>>>(Wq, f_w2, f_b2, gwih, gwhh, gbih, gbhh,
                                mw1, mb1, mw2, mb2, lnpg, lnpb,
                                lnsg, lnsb, ws, out, last);
  }
}

// Round 16
// 155.460 us; speedup vs baseline: 1.3725x; 1.0097x over previous
//
#include <hip/hip_runtime.h>
#include <cstdint>
#include <cstddef>

#define SCALE  0.08838834764831845f   // 128^-0.5
#define EPS_   1e-8f
#define LN_EPS_ 1e-5f

typedef unsigned short ushort_t;
typedef unsigned int uint_t;
typedef __attribute__((ext_vector_type(8))) short short8;
typedef __attribute__((ext_vector_type(4))) float f32x4;

// ---------------- workspace layout (float offsets), 23.3 MB ----------------
constexpr int OFF_GFD   = 0;        // 256   (f_w1@g_w)/DELTA  [h][2]
constexpr int OFF_CB    = 256;      // 128   f_w1@g_b + f_b1
constexpr int OFF_QB    = 384;      // 64
constexpr int OFF_SP    = 448;      // 128
constexpr int OFF_OQ    = 576;      // 16384 interleaved (off, qf*scale)
constexpr int OFF_SLOTS = 16960;    // 8192
constexpr int OFF_ZP    = 25152;    // 4096   [b][64][8]
constexpr int OFF_PP    = 29248;    // 8192   [b][64][8][2]
constexpr int OFF_UP    = 37440;    // 524288 [b][64][8][128]
constexpr int OFF_WKB   = 561728;   // bf16 [128][128] = 8192 float-slots
constexpr int OFF_WVB   = 569920;   // 8192
constexpr int OFF_FW2T  = 578112;   // f32 f_w2^T 16384
constexpr int OFF_BKT   = 594496;   // uint [b][64 dp][4096 n] = 2097152 float-slots
constexpr int OFF_BV    = 2691648;  // bf16 [b][4096][128] = 2097152 float-slots
constexpr int OFF_AB    = 4788800;  // bf16 inputs [32768][128] = 1048576 float-slots
// end: 5837376 floats

__device__ __forceinline__ float waveReduceSum(float v) {
#pragma unroll
  for (int m = 1; m < 64; m <<= 1) v += __shfl_xor(v, m, 64);
  return v;
}
__device__ __forceinline__ float bf2f(uint_t u) { return __uint_as_float(u << 16); }
__device__ __forceinline__ ushort_t f2bf(float f) {
  uint_t u = __float_as_uint(f);
  return (ushort_t)((u + 0x7fffu + ((u >> 16) & 1u)) >> 16);
}

// half-row dot (e-range [h*64, h*64+64)), 16 independent float4 loads
__device__ __forceinline__ float halfDot(const float* __restrict__ Wrow,
                                         const float* xv, int h) {
  const float4* wr = (const float4*)Wrow + h * 16;
  const float4* xr = (const float4*)xv + h * 16;
  float4 a = {0.f, 0.f, 0.f, 0.f};
#pragma unroll
  for (int i = 0; i < 16; ++i) {
    float4 wv = wr[i], xq = xr[i];
    a.x = fmaf(wv.x, xq.x, a.x);
    a.y = fmaf(wv.y, xq.y, a.y);
    a.z = fmaf(wv.z, xq.z, a.z);
    a.w = fmaf(wv.w, xq.w, a.w);
  }
  return (a.x + a.y) + (a.z + a.w);
}

// quarter-row dot (e-range [h*32, h*32+32)), 8 independent float4 loads
__device__ __forceinline__ float quarterDot(const float* __restrict__ Wrow,
                                            const float* xv, int h) {
  const float4* wr = (const float4*)Wrow + h * 8;
  const float4* xr = (const float4*)xv + h * 8;
  float4 a = {0.f, 0.f, 0.f, 0.f};
#pragma unroll
  for (int i = 0; i < 8; ++i) {
    float4 wv = wr[i], xq = xr[i];
    a.x = fmaf(wv.x, xq.x, a.x);
    a.y = fmaf(wv.y, xq.y, a.y);
    a.z = fmaf(wv.z, xq.z, a.z);
    a.w = fmaf(wv.w, xq.w, a.w);
  }
  return (a.x + a.y) + (a.z + a.w);
}
__device__ __forceinline__ float quadSum(float v) {
  v += __shfl_xor(v, 1, 64);
  v += __shfl_xor(v, 2, 64);
  return v;
}

// ---------------- fold weights + init copies + input cast + SrSs out ----------------
__global__ __launch_bounds__(256) void kFold(
    const float* __restrict__ f_w1, const float* __restrict__ Wk,
    const float* __restrict__ Wv, const float* __restrict__ g_w,
    const float* __restrict__ g_b, const float* __restrict__ f_b1,
    const float* __restrict__ f_w2, const float* __restrict__ slots_init,
    const float* __restrict__ S_p0, const float* __restrict__ inputs,
    const float* __restrict__ S_r, const float* __restrict__ S_s,
    float* __restrict__ ws, float* __restrict__ out) {
  int blk = blockIdx.x, tid = threadIdx.x;
  if (blk < 128) {
    int isV = blk >> 6;
    int idx = (blk & 63) * 256 + tid;           // 0..16383  (h*128+e)
    int h = idx >> 7, e = idx & 127;
    const float* Wm = isV ? Wv : Wk;
    float a = 0.f;
#pragma unroll 4
    for (int d = 0; d < 128; ++d) a = fmaf(f_w1[h * 128 + d], Wm[d * 128 + e], a);
    ((ushort_t*)(ws + (isV ? OFF_WVB : OFF_WKB)))[idx] = f2bf(a);
  } else if (blk == 128) {
    int h = tid >> 1, c = tid & 1;
    float a = 0.f;
    for (int d = 0; d < 128; ++d) a = fmaf(f_w1[h * 128 + d], g_w[d * 2 + c], a);
    ws[OFF_GFD + tid] = a * 0.2f;               // /DELTA (DELTA=5)
  } else if (blk == 129) {
    if (tid < 128) {
      float a = f_b1[tid];
      for (int d = 0; d < 128; ++d) a = fmaf(f_w1[tid * 128 + d], g_b[d], a);
      ws[OFF_CB + tid] = a;
    }
  } else if (blk == 130) {
    for (int i = tid; i < 16384; i += 256)
      ws[OFF_FW2T + (i & 127) * 128 + (i >> 7)] = f_w2[i];
  } else if (blk < 135) {
    int base = (blk - 131) * 2048 + tid * 8;    // slots copy, 8 floats/thread
    float4 a = *(const float4*)&slots_init[base];
    float4 b = *(const float4*)&slots_init[base + 4];
    *(float4*)&ws[OFF_SLOTS + base] = a;
    *(float4*)&ws[OFF_SLOTS + base + 4] = b;
  } else if (blk == 135) {
    if (tid < 128) ws[OFF_SP + tid] = S_p0[tid];
    else if (tid < 256) out[8576 + tid - 128] = S_s[tid - 128];
  } else if (blk == 136) {
    out[8320 + tid] = S_r[tid];
  } else {
    // input cast: blocks 137..392, 8 floats per thread
    int idx = (blk - 137) * 256 + tid;          // 0..65535
    const float4* src = (const float4*)(inputs + (size_t)idx * 8);
    float4 a = src[0], b = src[1];
    uint_t p0 = (uint_t)f2bf(a.x) | ((uint_t)f2bf(a.y) << 16);
    uint_t p1 = (uint_t)f2bf(a.z) | ((uint_t)f2bf(a.w) << 16);
    uint_t p2 = (uint_t)f2bf(b.x) | ((uint_t)f2bf(b.y) << 16);
    uint_t p3 = (uint_t)f2bf(b.z) | ((uint_t)f2bf(b.w) << 16);
    ((uint4*)((ushort_t*)(ws + OFF_AB)))[idx] = make_uint4(p0, p1, p2, p3);
  }
}

// ---------------- MFMA base GEMMs (64-row blocks) + initial q ----------------
struct QSm { float yl[128]; float ql[128]; float red[4]; float red2[4]; };

__device__ void doQ(int bs, const float* __restrict__ Wq,
                    const float* __restrict__ f_b2,
                    const float* __restrict__ lnsg,
                    const float* __restrict__ lnsb,
                    float* __restrict__ ws, QSm& S) {
  int t = threadIdx.x, w = t >> 6, lane = t & 63;
  int d = w * 32 + (lane >> 1), h = lane & 1;
  const float* FW2T = ws + OFF_FW2T;
  float x = ws[OFF_SLOTS + bs * 128 + d];
  float m1 = waveReduceSum(h == 0 ? x : 0.f);
  float m2 = waveReduceSum(h == 0 ? x * x : 0.f);
  if (lane == 0) { S.red[w] = m1; S.red2[w] = m2; }
  __syncthreads();
  float mean = (S.red[0] + S.red[1] + S.red[2] + S.red[3]) * (1.f / 128.f);
  float var = (S.red2[0] + S.red2[1] + S.red2[2] + S.red2[3]) * (1.f / 128.f) - mean * mean;
  if (h == 0) S.yl[d] = (x - mean) * rsqrtf(var + LN_EPS_) * lnsg[d] + lnsb[d];
  __syncthreads();
  float q = halfDot(Wq + (size_t)d * 128, S.yl, h);
  q += __shfl_xor(q, 1, 64);
  if (h == 0) S.ql[d] = q;
  __syncthreads();
  float qv = waveReduceSum(h == 0 ? q * f_b2[d] : 0.f);
  if (lane == 0) S.red[w] = qv;
  float qf = halfDot(FW2T + (size_t)d * 128, S.ql, h);
  qf += __shfl_xor(qf, 1, 64);
  __syncthreads();
  if (t == 0) ws[OFF_QB + bs] = (S.red[0] + S.red[1] + S.red[2] + S.red[3]) * SCALE;
  if (h == 0) {
    float sp0 = ws[OFF_SP + bs * 2 + 0], sp1 = ws[OFF_SP + bs * 2 + 1];
    float offd = -(sp0 * ws[OFF_GFD + d * 2 + 0] + sp1 * ws[OFF_GFD + d * 2 + 1]);
    ws[OFF_OQ + (bs * 128 + d) * 2 + 0] = offd;
    ws[OFF_OQ + (bs * 128 + d) * 2 + 1] = qf * SCALE;
  }
}

// grid: 1024 GEMM blocks (mat = blk>>9, rb = blk&511, 64 rows each) + 64 doQ
__global__ __launch_bounds__(256) void kBaseQ(const float* __restrict__ Wq,
                                              const float* __restrict__ f_b2,
                                              const float* __restrict__ lnsg,
                                              const float* __restrict__ lnsb,
                                              float* __restrict__ ws) {
  __shared__ __align__(16) char smem[17408];
  int blk = blockIdx.x;
  if (blk >= 1024) {      // initial q projection blocks
    doQ(blk - 1024, Wq, f_b2, lnsg, lnsb, ws, *reinterpret_cast<QSm*>(smem));
    return;
  }
  char* ep = smem;
  const ushort_t* ab = (const ushort_t*)(ws + OFF_AB);
  int tid = threadIdx.x, w = tid >> 6, l = tid & 63;
  int lr = l & 15, lg = l >> 4;
  int mat = blk >> 9;
  int rb = blk & 511;                 // 0..511 (64-row block index)
  int b = rb >> 6;
  int n0 = (rb & 63) * 64;            // pixel base within batch
  const ushort_t* Wg = (const ushort_t*)(ws + (mat ? OFF_WVB : OFF_WKB));

  short8 afrag[4];
#pragma unroll
  for (int ks = 0; ks < 4; ++ks) {
    size_t row = (size_t)b * 4096 + n0 + w * 16 + lr;
    afrag[ks] = *(const short8*)(ab + row * 128 + ks * 32 + lg * 8);
  }
  float gf0a[8], gf1a[8], cba[8];
#pragma unroll
  for (int ct = 0; ct < 8; ++ct) {
    int c = ct * 16 + lr;
    gf0a[ct] = ws[OFF_GFD + c * 2 + 0];
    gf1a[ct] = ws[OFF_GFD + c * 2 + 1];
    cba[ct]  = ws[OFF_CB + c];
  }
  f32x4 acc[8];
#pragma unroll
  for (int ct = 0; ct < 8; ++ct) acc[ct] = (f32x4){0.f, 0.f, 0.f, 0.f};
  // deep-ILP main loop: 4 independent ct streams of loads+MFMAs in flight
#pragma unroll 4
  for (int ct = 0; ct < 8; ++ct) {
    short8 bfr[4];
#pragma unroll
    for (int ks = 0; ks < 4; ++ks)
      bfr[ks] = *(const short8*)(Wg + (ct * 16 + lr) * 128 + ks * 32 + lg * 8);
#pragma unroll
    for (int ks = 0; ks < 4; ++ks)
      acc[ct] = __builtin_amdgcn_mfma_f32_16x16x32_bf16(afrag[ks], bfr[ks], acc[ct], 0, 0, 0);
  }
#pragma unroll
  for (int ct = 0; ct < 8; ++ct) {
    int c = ct * 16 + lr;
    ushort_t pk[4];
#pragma unroll
    for (int r = 0; r < 4; ++r) {
      int nl = w * 16 + lg * 4 + r;
      int n = n0 + nl;
      float gy = -1.f + (float)(n >> 6) * (2.f / 63.f);
      float gx = -1.f + (float)(n & 63) * (2.f / 63.f);
      float o = acc[ct][r] + gy * gf0a[ct] + gx * gf1a[ct] + cba[ct];
      pk[r] = f2bf(o);
    }
    if (mat == 0) {
      int nl0 = w * 16 + lg * 4;
      int byte = (c * 128 + nl0 * 2) ^ ((c & 7) << 4);
      *(uint2*)(ep + byte) = make_uint2(
          (uint_t)pk[0] | ((uint_t)pk[1] << 16),
          (uint_t)pk[2] | ((uint_t)pk[3] << 16));
    } else {
      int nl0 = w * 16 + lg * 4;
#pragma unroll
      for (int r = 0; r < 4; ++r)
        *(ushort_t*)(ep + (nl0 + r) * 272 + c * 2) = pk[r];
    }
  }
  __syncthreads();
  if (mat == 0) {
    uint_t* outK = (uint_t*)(ws + OFF_BKT);
    for (int idx = tid; idx < 1024; idx += 256) {
      int dp = idx >> 4, j = idx & 15;
      int c0 = 2 * dp, c1 = 2 * dp + 1;
      uint2 aA = *(const uint2*)(ep + ((c0 * 128 + j * 8) ^ ((c0 & 7) << 4)));
      uint2 bA = *(const uint2*)(ep + ((c1 * 128 + j * 8) ^ ((c1 & 7) << 4)));
      uint4 o;
      o.x = (aA.x & 0xffffu) | (bA.x << 16);
      o.y = (aA.x >> 16) | (bA.x & 0xffff0000u);
      o.z = (aA.y & 0xffffu) | (bA.y << 16);
      o.w = (aA.y >> 16) | (bA.y & 0xffff0000u);
      *(uint4*)(outK + ((size_t)(b * 64 + dp)) * 4096 + n0 + j * 4) = o;
    }
  } else {
    ushort_t* outV = (ushort_t*)(ws + OFF_BV);
    for (int idx = tid; idx < 1024; idx += 256) {
      int nl = idx >> 4, j = idx & 15;
      uint4 v = *(const uint4*)(ep + nl * 272 + j * 16);
      *(uint4*)(outV + ((size_t)rb * 64 + nl) * 128 + j * 8) = v;
    }
  }
}

// ---------------- fused attention: 4 waves, K+V prefetch, distributed Z/P ----------------
__global__ __launch_bounds__(256) void kAttn(float* __restrict__ ws) {
  __shared__ __align__(16) float OFFl[8][128];
  __shared__ __align__(16) float QFl[8][128];
  __shared__ float tp[64][37];
  __shared__ __align__(16) float al[64][12];
  __shared__ float Ush[4][8][132];
  int b = blockIdx.x >> 6, chunk = blockIdx.x & 63;
  int tid = threadIdx.x, w = tid >> 6, lane = tid & 63;
  int sb = b * 8;
  int n = chunk * 64 + lane;
  // prefetch: all 16 K-loads + all 16 V-loads issued up front
  const uint_t* kpp = (const uint_t*)(ws + OFF_BKT) +
                      (size_t)b * 262144 + (size_t)(w * 16) * 4096 + n;
  uint_t karr[16];
#pragma unroll
  for (int dp = 0; dp < 16; ++dp) karr[dp] = kpp[(size_t)dp * 4096];
  int c0 = 2 * lane;
  const ushort_t* vp = (const ushort_t*)(ws + OFF_BV) +
                       ((size_t)(b * 4096 + chunk * 64 + w * 16)) * 128 + c0;
  uint_t varr[16];
#pragma unroll
  for (int i = 0; i < 16; ++i) varr[i] = *(const uint_t*)(vp + (size_t)i * 128);
  for (int f = tid; f < 1024; f += 256) {
    int s = f >> 7, d = f & 127;
    float2 oq = *(const float2*)&ws[OFF_OQ + ((sb + s) * 128 + d) * 2];
    OFFl[s][d] = oq.x;
    QFl[s][d] = oq.y;
  }
  float qbl[8];
#pragma unroll
  for (int s = 0; s < 8; ++s) qbl[s] = ws[OFF_QB + sb + s];
  __syncthreads();

  // phase 1: pixel-per-lane dots over prefetched K
  float t[8];
#pragma unroll
  for (int s = 0; s < 8; ++s) t[s] = 0.f;
#pragma unroll
  for (int dp = 0; dp < 16; ++dp) {
    uint_t v = karr[dp];
    float k0 = bf2f(v & 0xffffu);
    float k1 = bf2f(v >> 16);
    int d0 = w * 32 + 2 * dp;
#pragma unroll
    for (int s = 0; s < 8; ++s) {
      float2 ofp = *(const float2*)&OFFl[s][d0];
      float2 qfp = *(const float2*)&QFl[s][d0];
      t[s] = fmaf(fmaxf(k0 + ofp.x, 0.f), qfp.x, t[s]);
      t[s] = fmaf(fmaxf(k1 + ofp.y, 0.f), qfp.y, t[s]);
    }
  }
#pragma unroll
  for (int s = 0; s < 8; ++s) tp[lane][s * 4 + w] = t[s];
  __syncthreads();
  float a[8], den = 0.f;
#pragma unroll
  for (int s = 0; s < 8; ++s)
    t[s] = tp[lane][s * 4 + 0] + tp[lane][s * 4 + 1] +
           tp[lane][s * 4 + 2] + tp[lane][s * 4 + 3] + qbl[s];
  float mx = t[0];
#pragma unroll
  for (int s = 1; s < 8; ++s) mx = fmaxf(mx, t[s]);
#pragma unroll
  for (int s = 0; s < 8; ++s) { a[s] = __expf(t[s] - mx); den += a[s]; }
  float inv = 1.0f / den;
#pragma unroll
  for (int s = 0; s < 8; ++s) a[s] = fmaf(a[s], inv, EPS_);
  // distributed Z/P: every wave holds identical a[]; wave w reduces slots 2w,2w+1
  {
    float gy = -1.f + (float)(n >> 6) * (2.f / 63.f);
    float gx = -1.f + (float)(n & 63) * (2.f / 63.f);
    if (w == 0) {
#pragma unroll
      for (int s = 0; s < 8; ++s) al[lane][s] = a[s];
    }
#pragma unroll
    for (int k = 0; k < 2; ++k) {
      int s = w * 2 + k;
      float z = waveReduceSum(a[s]);
      float p0 = waveReduceSum(a[s] * gy);
      float p1 = waveReduceSum(a[s] * gx);
      if (lane == 0) {
        ws[OFF_ZP + (b * 64 + chunk) * 8 + s] = z;
        ws[OFF_PP + ((b * 64 + chunk) * 8 + s) * 2 + 0] = p0;
        ws[OFF_PP + ((b * 64 + chunk) * 8 + s) * 2 + 1] = p1;
      }
    }
  }
  __syncthreads();

  // phase 2: channel-pair-per-lane over this wave's 16 pixels (V prefetched)
  float offv0[8], offv1[8];
#pragma unroll
  for (int s = 0; s < 8; ++s) {
    float2 of2 = *(const float2*)&OFFl[s][c0];
    offv0[s] = of2.x;
    offv1[s] = of2.y;
  }
  float Ua0[8], Ua1[8];
#pragma unroll
  for (int s = 0; s < 8; ++s) { Ua0[s] = 0.f; Ua1[s] = 0.f; }
#pragma unroll 4
  for (int i = 0; i < 16; ++i) {
    uint_t vraw = varr[i];
    float v0 = bf2f(vraw & 0xffffu);
    float v1 = bf2f(vraw >> 16);
    int ii = w * 16 + i;
    float4 a0 = *(const float4*)&al[ii][0];
    float4 a1 = *(const float4*)&al[ii][4];
    float asv[8] = {a0.x, a0.y, a0.z, a0.w, a1.x, a1.y, a1.z, a1.w};
#pragma unroll
    for (int s = 0; s < 8; ++s) {
      Ua0[s] = fmaf(asv[s], fmaxf(v0 + offv0[s], 0.f), Ua0[s]);
      Ua1[s] = fmaf(asv[s], fmaxf(v1 + offv1[s], 0.f), Ua1[s]);
    }
  }
#pragma unroll
  for (int s = 0; s < 8; ++s) {
    Ush[w][s][c0] = Ua0[s];
    Ush[w][s][c0 + 1] = Ua1[s];
  }
  __syncthreads();
  for (int f = tid; f < 1024; f += 256) {
    int s = f >> 7, c = f & 127;
    float v = Ush[0][s][c] + Ush[1][s][c] + Ush[2][s][c] + Ush[3][s][c];
    ws[OFF_UP + ((size_t)(b * 64 + chunk) * 8 + s) * 128 + c] = v;
  }
}

// ---------------- fused: finalize + GRU + post-MLP + next-iter q ----------------
__global__ __launch_bounds__(512) void kCQ(
    const float* __restrict__ Wq, const float* __restrict__ f_w2,
    const float* __restrict__ f_b2, const float* __restrict__ wih,
    const float* __restrict__ whh, const float* __restrict__ bih,
    const float* __restrict__ bhh, const float* __restrict__ mw1,
    const float* __restrict__ mb1, const float* __restrict__ mw2,
    const float* __restrict__ mb2, const float* __restrict__ lnpg,
    const float* __restrict__ lnpb, const float* __restrict__ lnsg,
    const float* __restrict__ lnsb, float* __restrict__ ws,
    float* __restrict__ out, int last) {
  int bs = blockIdx.x;
  int t = threadIdx.x;
  int b = bs >> 3, s = bs & 7;
  int w = t >> 6, lane = t & 63;
  int d = t >> 2, h = t & 3;
  __shared__ __align__(16) float ul[128], xl[128], sl[128], yl[128], hml[128];
  __shared__ float red[8], red2[8];
  const float* FW2T = ws + OFF_FW2T;
  float zv = ws[OFF_ZP + (b * 64 + lane) * 8 + s];
  float2 pv = *(const float2*)&ws[OFF_PP + ((size_t)(b * 64 + lane) * 8 + s) * 2];
  float Z = waveReduceSum(zv);
  float P0 = waveReduceSum(pv.x);
  float P1 = waveReduceSum(pv.y);
  float invZ = 1.f / Z, sp0 = P0 * invZ, sp1 = P1 * invZ;
  float u = 0.f;
  const float* up = ws + OFF_UP + ((size_t)(b * 64 + h * 16) * 8 + s) * 128 + d;
#pragma unroll
  for (int ch = 0; ch < 16; ++ch) u += up[(size_t)ch * 1024];
  u = quadSum(u);
  if (h == 0) { ul[d] = u * invZ; sl[d] = ws[OFF_SLOTS + bs * 128 + d]; }
  if (t == 0) {
    ws[OFF_SP + bs * 2 + 0] = sp0;
    ws[OFF_SP + bs * 2 + 1] = sp1;
    if (last) {
      out[8192 + bs * 2 + 0] = sp0;
      out[8192 + bs * 2 + 1] = sp1;
    }
  }
  __syncthreads();
  float xa = quadSum(quarterDot(f_w2 + (size_t)d * 128, ul, h));
  if (h == 0) xl[d] = xa + f_b2[d];
  __syncthreads();
  float ir = quarterDot(wih + (size_t)d * 128, xl, h);
  float iz = quarterDot(wih + (size_t)(128 + d) * 128, xl, h);
  float in_ = quarterDot(wih + (size_t)(256 + d) * 128, xl, h);
  float hr = quarterDot(whh + (size_t)d * 128, sl, h);
  float hz = quarterDot(whh + (size_t)(128 + d) * 128, sl, h);
  float hn = quarterDot(whh + (size_t)(256 + d) * 128, sl, h);
  ir = quadSum(ir); iz = quadSum(iz); in_ = quadSum(in_);
  hr = quadSum(hr); hz = quadSum(hz); hn = quadSum(hn);
  float hnew = 0.f;
  if (h == 0) {
    float rg = 1.f / (1.f + __expf(-(ir + bih[d] + hr + bhh[d])));
    float zg = 1.f / (1.f + __expf(-(iz + bih[128 + d] + hz + bhh[128 + d])));
    float ng = tanhf(in_ + bih[256 + d] + rg * (hn + bhh[256 + d]));
    hnew = (1.f - zg) * ng + zg * sl[d];
  }
  float m1 = waveReduceSum(h == 0 ? hnew : 0.f);
  float m2 = waveReduceSum(h == 0 ? hnew * hnew : 0.f);
  if (lane == 0) { red[w] = m1; red2[w] = m2; }
  __syncthreads();
  float mean = 0.f, var = 0.f;
#pragma unroll
  for (int i = 0; i < 8; ++i) { mean += red[i]; var += red2[i]; }
  mean *= (1.f / 128.f);
  var = var * (1.f / 128.f) - mean * mean;
  if (h == 0) yl[d] = (hnew - mean) * rsqrtf(var + LN_EPS_) * lnpg[d] + lnpb[d];
  __syncthreads();
  float hm = quadSum(quarterDot(mw1 + (size_t)d * 128, yl, h));
  if (h == 0) hml[d] = fmaxf(hm + mb1[d], 0.f);
  __syncthreads();
  float oa = quadSum(quarterDot(mw2 + (size_t)d * 128, hml, h));
  float o = 0.f;
  if (h == 0) {
    o = hnew + mb2[d] + oa;
    ws[OFF_SLOTS + bs * 128 + d] = o;
    if (last) out[bs * 128 + d] = o;
  }
  float n1 = waveReduceSum(h == 0 ? o : 0.f);
  float n2 = waveReduceSum(h == 0 ? o * o : 0.f);
  if (lane == 0) { red[w] = n1; red2[w] = n2; }
  __syncthreads();
  float mean2 = 0.f, var2 = 0.f;
#pragma unroll
  for (int i = 0; i < 8; ++i) { mean2 += red[i]; var2 += red2[i]; }
  mean2 *= (1.f / 128.f);
  var2 = var2 * (1.f / 128.f) - mean2 * mean2;
  if (h == 0) yl[d] = (o - mean2) * rsqrtf(var2 + LN_EPS_) * lnsg[d] + lnsb[d];
  __syncthreads();
  float q = quadSum(quarterDot(Wq + (size_t)d * 128, yl, h));
  if (h == 0) xl[d] = q;
  __syncthreads();
  float qv = waveReduceSum(h == 0 ? q * f_b2[d] : 0.f);
  if (lane == 0) red[w] = qv;
  float qf = quadSum(quarterDot(FW2T + (size_t)d * 128, xl, h));
  __syncthreads();
  if (t == 0) {
    float qb = 0.f;
#pragma unroll
    for (int i = 0; i < 8; ++i) qb += red[i];
    ws[OFF_QB + bs] = qb * SCALE;
  }
  if (h == 0) {
    float offd = -(sp0 * ws[OFF_GFD + d * 2 + 0] + sp1 * ws[OFF_GFD + d * 2 + 1]);
    ws[OFF_OQ + (bs * 128 + d) * 2 + 0] = offd;
    ws[OFF_OQ + (bs * 128 + d) * 2 + 1] = qf * SCALE;
  }
}

extern "C" void kernel_launch(void* const* d_in, const int* in_sizes, int n_in,
                              void* d_out, int out_size, void* d_ws, size_t ws_size,
                              hipStream_t stream) {
  const float* inputs     = (const float*)d_in[0];
  const float* slots_init = (const float*)d_in[1];
  const float* S_p0       = (const float*)d_in[2];
  const float* S_s        = (const float*)d_in[3];
  const float* S_r        = (const float*)d_in[4];
  const float* Wq   = (const float*)d_in[5];
  const float* Wk   = (const float*)d_in[6];
  const float* Wv   = (const float*)d_in[7];
  const float* g_w  = (const float*)d_in[8];
  const float* g_b  = (const float*)d_in[9];
  const float* f_w1 = (const float*)d_in[10];
  const float* f_b1 = (const float*)d_in[11];
  const float* f_w2 = (const float*)d_in[12];
  const float* f_b2 = (const float*)d_in[13];
  const float* gwih = (const float*)d_in[14];
  const float* gwhh = (const float*)d_in[15];
  const float* gbih = (const float*)d_in[16];
  const float* gbhh = (const float*)d_in[17];
  const float* mw1  = (const float*)d_in[18];
  const float* mb1  = (const float*)d_in[19];
  const float* mw2  = (const float*)d_in[20];
  const float* mb2  = (const float*)d_in[21];
  const float* lnsg = (const float*)d_in[22];
  const float* lnsb = (const float*)d_in[23];
  const float* lnpg = (const float*)d_in[24];
  const float* lnpb = (const float*)d_in[25];
  float* ws  = (float*)d_ws;
  float* out = (float*)d_out;

  kFold<<<393, 256, 0, stream>>>(f_w1, Wk, Wv, g_w, g_b, f_b1, f_w2,
                                 slots_init, S_p0, inputs, S_r, S_s, ws, out);
  kBaseQ<<<1088, 256, 0, stream>>>(Wq, f_b2, lnsg, lnsb, ws);
  for (int it = 0; it < 3; ++it) {
    int last = (it == 2);
    kAttn<<<512, 256, 0, stream>>>(ws);
    kCQ<<<64, 512, 0, stream>>>(Wq, f_w2, f_b2, gwih, gwhh, gbih, gbhh,
                                mw1, mb1, mw2, mb2, lnpg, lnpb,
                                lnsg, lnsb, ws, out, last);
  }
}